// Round 1
// baseline (260.331 us; speedup 1.0000x reference)
//
#include <hip/hip_runtime.h>
#include <hip/hip_bf16.h>

typedef unsigned int uint32;
typedef unsigned short ushort_t;

typedef __bf16 bf16x8 __attribute__((ext_vector_type(8)));
typedef float f32x4 __attribute__((ext_vector_type(4)));

// fp32 -> bf16 round-to-nearest-even (finite inputs only)
__device__ __forceinline__ ushort_t f2bf(float f) {
    uint32 u = __float_as_uint(f);
    u += 0x7fffu + ((u >> 16) & 1u);
    return (ushort_t)(u >> 16);
}
__device__ __forceinline__ float bf2f(ushort_t h) {
    return __uint_as_float(((uint32)h) << 16);
}

union U16 { int4 v; ushort_t u[8]; };

// ---------------------------------------------------------------------------
// Shared GEMM micro-structure: 128x128 tile, BK=32, 4 waves (2x2 of 64x64),
// mfma_f32_16x16x32_bf16, LDS row stride 40 (2-way bank alias = free).
// A and B tile-base pointers are pre-offset; both K-contiguous (gemm_bt form).
// ---------------------------------------------------------------------------
__device__ __forceinline__ void gemm_step_bf16(
    const ushort_t* __restrict__ A, int lda,
    const ushort_t* __restrict__ Bm, int ldb, int k0,
    ushort_t* As, ushort_t* Bs, int tid, f32x4 acc[4][4])
{
    // stage A: 128 rows x 32 cols bf16 -> LDS (512 chunks of 8 elems)
#pragma unroll
    for (int i = 0; i < 2; ++i) {
        int c = tid + 256 * i;
        int row = c >> 2, col8 = c & 3;
        *(int4*)&As[row * 40 + col8 * 8] =
            *(const int4*)&A[(size_t)row * lda + k0 + col8 * 8];
    }
#pragma unroll
    for (int i = 0; i < 2; ++i) {
        int c = tid + 256 * i;
        int row = c >> 2, col8 = c & 3;
        *(int4*)&Bs[row * 40 + col8 * 8] =
            *(const int4*)&Bm[(size_t)row * ldb + k0 + col8 * 8];
    }
    __syncthreads();
    const int lane = tid & 63, wid = tid >> 6;
    const int wr = wid >> 1, wc = wid & 1;
    const int koff = (lane >> 4) * 8;
    bf16x8 a[4], bb[4];
#pragma unroll
    for (int m = 0; m < 4; ++m)
        a[m] = *(const bf16x8*)&As[(wr * 64 + m * 16 + (lane & 15)) * 40 + koff];
#pragma unroll
    for (int n = 0; n < 4; ++n)
        bb[n] = *(const bf16x8*)&Bs[(wc * 64 + n * 16 + (lane & 15)) * 40 + koff];
#pragma unroll
    for (int m = 0; m < 4; ++m)
#pragma unroll
        for (int n = 0; n < 4; ++n)
            acc[m][n] = __builtin_amdgcn_mfma_f32_16x16x32_bf16(a[m], bb[n], acc[m][n], 0, 0, 0);
    __syncthreads();
}

// epilogue: verified C/D layout col=lane&15, row=(lane>>4)*4+j
__device__ __forceinline__ void store_tile_bf16(
    ushort_t* __restrict__ Dst, int ldd, int tid, const f32x4 acc[4][4], float scale)
{
    const int lane = tid & 63, wid = tid >> 6;
    const int wr = wid >> 1, wc = wid & 1;
#pragma unroll
    for (int m = 0; m < 4; ++m)
#pragma unroll
        for (int n = 0; n < 4; ++n)
#pragma unroll
            for (int j = 0; j < 4; ++j) {
                int row = wr * 64 + m * 16 + (lane >> 4) * 4 + j;
                int col = wc * 64 + n * 16 + (lane & 15);
                Dst[(size_t)row * ldd + col] = f2bf(acc[m][n][j] * scale);
            }
}

// ---------------------------------------------------------------------------
// Kernel 1: QKV projection. X fp32 [8192][1024], W fp32 [1024][1024] (d_out,d_in)
// -> bf16 [8192][1024]. grid (N/128=8, M/128=64, 3). fp32->bf16 fused in staging.
// ---------------------------------------------------------------------------
__global__ __launch_bounds__(256) void qkv_gemm(
    const float* __restrict__ X,
    const float* __restrict__ Wq, const float* __restrict__ Wk,
    const float* __restrict__ Wv, ushort_t* __restrict__ QKV)
{
    const int z = blockIdx.z;
    const float* W = (z == 0) ? Wq : ((z == 1) ? Wk : Wv);
    ushort_t* Dst = QKV + (size_t)z * 8192 * 1024;
    const int bm = blockIdx.y, bn = blockIdx.x;
    const int tid = threadIdx.x;
    __shared__ __align__(16) ushort_t As[128 * 40];
    __shared__ __align__(16) ushort_t Bs[128 * 40];
    const float* Xa = X + (size_t)bm * 128 * 1024;
    const float* Wb = W + (size_t)bn * 128 * 1024;
    f32x4 acc[4][4] = {};
    for (int k0 = 0; k0 < 1024; k0 += 32) {
        // stage with fused fp32->bf16: 128x32 floats each, 4 float4 chunks/thread
#pragma unroll
        for (int i = 0; i < 4; ++i) {
            int c = tid + 256 * i;            // 0..1023
            int row = c >> 3, col4 = c & 7;   // 8 chunks of 4 per row
            float4 f = *(const float4*)&Xa[(size_t)row * 1024 + k0 + col4 * 4];
            ushort4 h;
            h.x = f2bf(f.x); h.y = f2bf(f.y); h.z = f2bf(f.z); h.w = f2bf(f.w);
            *(ushort4*)&As[row * 40 + col4 * 4] = h;
        }
#pragma unroll
        for (int i = 0; i < 4; ++i) {
            int c = tid + 256 * i;
            int row = c >> 3, col4 = c & 7;
            float4 f = *(const float4*)&Wb[(size_t)row * 1024 + k0 + col4 * 4];
            ushort4 h;
            h.x = f2bf(f.x); h.y = f2bf(f.y); h.z = f2bf(f.z); h.w = f2bf(f.w);
            *(ushort4*)&Bs[row * 40 + col4 * 4] = h;
        }
        __syncthreads();
        const int lane = tid & 63, wid = tid >> 6;
        const int wr = wid >> 1, wc = wid & 1;
        const int koff = (lane >> 4) * 8;
        bf16x8 a[4], bb[4];
#pragma unroll
        for (int m = 0; m < 4; ++m)
            a[m] = *(const bf16x8*)&As[(wr * 64 + m * 16 + (lane & 15)) * 40 + koff];
#pragma unroll
        for (int n = 0; n < 4; ++n)
            bb[n] = *(const bf16x8*)&Bs[(wc * 64 + n * 16 + (lane & 15)) * 40 + koff];
#pragma unroll
        for (int m = 0; m < 4; ++m)
#pragma unroll
            for (int n = 0; n < 4; ++n)
                acc[m][n] = __builtin_amdgcn_mfma_f32_16x16x32_bf16(a[m], bb[n], acc[m][n], 0, 0, 0);
        __syncthreads();
    }
    store_tile_bf16(Dst + (size_t)bm * 128 * 1024 + bn * 128, 1024, tid, acc, 1.0f);
}

// ---------------------------------------------------------------------------
// Kernel 2: scores S = (Q @ K^T) / 32, bf16 out. Causal block-skip (bn > bm).
// grid (16,16,4). Masking deferred to softmax (by index).
// ---------------------------------------------------------------------------
__global__ __launch_bounds__(256) void scores_gemm(
    const ushort_t* __restrict__ Q, const ushort_t* __restrict__ Kb,
    ushort_t* __restrict__ P)
{
    const int b = blockIdx.z;
    const int bm = blockIdx.y, bn = blockIdx.x;
    if (bn > bm) return;  // fully masked tile
    const int tid = threadIdx.x;
    __shared__ __align__(16) ushort_t As[128 * 40];
    __shared__ __align__(16) ushort_t Bs[128 * 40];
    const ushort_t* A = Q + (size_t)b * 2048 * 1024 + (size_t)bm * 128 * 1024;
    const ushort_t* Bm = Kb + (size_t)b * 2048 * 1024 + (size_t)bn * 128 * 1024;
    f32x4 acc[4][4] = {};
    for (int k0 = 0; k0 < 1024; k0 += 32)
        gemm_step_bf16(A, 1024, Bm, 1024, k0, As, Bs, tid, acc);
    ushort_t* Pb = P + (size_t)b * 2048 * 2048 + (size_t)bm * 128 * 2048 + bn * 128;
    store_tile_bf16(Pb, 2048, tid, acc, 0.03125f);  // 1/sqrt(1024)
}

// ---------------------------------------------------------------------------
// Kernel 3: row softmax in place on P (bf16), causal mask by index.
// Writes exact 0 for masked entries -> PV reads a fully defined buffer.
// grid (2048, 4), 256 threads, 8 elems/thread.
// ---------------------------------------------------------------------------
__global__ __launch_bounds__(256) void softmax_rows(ushort_t* __restrict__ P)
{
    const int q = blockIdx.x, b = blockIdx.y;
    ushort_t* row = P + ((size_t)b * 2048 + q) * 2048;
    const int tid = threadIdx.x;
    U16 in;
    in.v = *(const int4*)&row[tid * 8];
    float v[8];
    float m = -3.0e38f;
#pragma unroll
    for (int j = 0; j < 8; ++j) {
        int k = tid * 8 + j;
        float s = bf2f(in.u[j]);
        v[j] = (k <= q) ? s : -3.0e38f;
        m = fmaxf(m, v[j]);
    }
#pragma unroll
    for (int off = 32; off >= 1; off >>= 1) m = fmaxf(m, __shfl_xor(m, off));
    __shared__ float red[4];
    if ((tid & 63) == 0) red[tid >> 6] = m;
    __syncthreads();
    m = fmaxf(fmaxf(red[0], red[1]), fmaxf(red[2], red[3]));
    float e[8], s = 0.f;
#pragma unroll
    for (int j = 0; j < 8; ++j) {
        e[j] = (v[j] > -1.0e38f) ? __expf(v[j] - m) : 0.f;
        s += e[j];
    }
#pragma unroll
    for (int off = 32; off >= 1; off >>= 1) s += __shfl_xor(s, off);
    __syncthreads();  // red reuse
    if ((tid & 63) == 0) red[tid >> 6] = s;
    __syncthreads();
    s = red[0] + red[1] + red[2] + red[3];
    float inv = 1.f / s;
    U16 outv;
#pragma unroll
    for (int j = 0; j < 8; ++j) outv.u[j] = f2bf(e[j] * inv);
    *(int4*)&row[tid * 8] = outv.v;
}

// ---------------------------------------------------------------------------
// Kernel 4: V transpose per batch: Vt[b][d][k] = V[b][k][d]. 64x64 LDS tiles.
// grid (32, 16, 4).
// ---------------------------------------------------------------------------
__global__ __launch_bounds__(256) void transpose_v(
    const ushort_t* __restrict__ V, ushort_t* __restrict__ Vt)
{
    __shared__ ushort_t ts[64][72];
    const int b = blockIdx.z;
    const ushort_t* Vb = V + (size_t)b * 2048 * 1024;
    ushort_t* Vtb = Vt + (size_t)b * 1024 * 2048;
    const int k0 = blockIdx.x * 64, d0 = blockIdx.y * 64;
    const int tid = threadIdx.x;
#pragma unroll
    for (int i = 0; i < 2; ++i) {
        int c = tid + 256 * i;
        int row = c >> 3, col8 = c & 7;
        U16 vv;
        vv.v = *(const int4*)&Vb[(size_t)(k0 + row) * 1024 + d0 + col8 * 8];
#pragma unroll
        for (int j = 0; j < 8; ++j) ts[row][col8 * 8 + j] = vv.u[j];
    }
    __syncthreads();
#pragma unroll
    for (int i = 0; i < 2; ++i) {
        int c = tid + 256 * i;
        int drow = c >> 3, kcol8 = c & 7;
        U16 vv;
#pragma unroll
        for (int j = 0; j < 8; ++j) vv.u[j] = ts[kcol8 * 8 + j][drow];
        *(int4*)&Vtb[(size_t)(d0 + drow) * 2048 + k0 + kcol8 * 8] = vv.v;
    }
}

// ---------------------------------------------------------------------------
// Kernel 5: O = P @ V  via Vt (gemm_bt). K capped at diagonal. fp32 out.
// grid (8, 16, 4).
// ---------------------------------------------------------------------------
__global__ __launch_bounds__(256) void pv_gemm(
    const ushort_t* __restrict__ P, const ushort_t* __restrict__ Vt,
    float* __restrict__ O)
{
    const int b = blockIdx.z;
    const int bm = blockIdx.y;  // q tile
    const int bn = blockIdx.x;  // d tile
    const int tid = threadIdx.x;
    __shared__ __align__(16) ushort_t As[128 * 40];
    __shared__ __align__(16) ushort_t Bs[128 * 40];
    const ushort_t* A = P + (size_t)b * 2048 * 2048 + (size_t)bm * 128 * 2048;
    const ushort_t* Bm = Vt + (size_t)b * 1024 * 2048 + (size_t)bn * 128 * 2048;
    f32x4 acc[4][4] = {};
    const int kEnd = (bm + 1) * 128;  // P[q][k]=0 beyond diagonal
    for (int k0 = 0; k0 < kEnd; k0 += 32)
        gemm_step_bf16(A, 2048, Bm, 2048, k0, As, Bs, tid, acc);
    float* Ob = O + (size_t)b * 2048 * 1024 + (size_t)bm * 128 * 1024 + bn * 128;
    const int lane = tid & 63, wid = tid >> 6;
    const int wr = wid >> 1, wc = wid & 1;
#pragma unroll
    for (int m = 0; m < 4; ++m)
#pragma unroll
        for (int n = 0; n < 4; ++n)
#pragma unroll
            for (int j = 0; j < 4; ++j) {
                int row = wr * 64 + m * 16 + (lane >> 4) * 4 + j;
                int col = wc * 64 + n * 16 + (lane & 15);
                Ob[(size_t)row * 1024 + col] = acc[m][n][j];
            }
}

// ---------------------------------------------------------------------------
// Workspace layout (bf16 elems):
//   q   [8192][1024]   @ 0
//   k   [8192][1024]   @ 8M
//   v   [8192][1024]   @ 16M
//   vt  [4][1024][2048]@ 24M
//   P   [4][2048][2048]@ 32M   (ends at 48M elems = 96 MB)
// ---------------------------------------------------------------------------
extern "C" void kernel_launch(void* const* d_in, const int* in_sizes, int n_in,
                              void* d_out, int out_size, void* d_ws, size_t ws_size,
                              hipStream_t stream) {
    const float* x  = (const float*)d_in[0];
    const float* Wq = (const float*)d_in[1];
    const float* Wk = (const float*)d_in[2];
    const float* Wv = (const float*)d_in[3];
    float* out = (float*)d_out;
    ushort_t* ws = (ushort_t*)d_ws;
    ushort_t* qb = ws;
    ushort_t* kb = qb + (size_t)8192 * 1024;
    ushort_t* vb = kb + (size_t)8192 * 1024;
    ushort_t* vt = vb + (size_t)8192 * 1024;
    ushort_t* P  = vt + (size_t)8192 * 1024;

    qkv_gemm<<<dim3(8, 64, 3), 256, 0, stream>>>(x, Wq, Wk, Wv, qb);
    scores_gemm<<<dim3(16, 16, 4), 256, 0, stream>>>(qb, kb, P);
    softmax_rows<<<dim3(2048, 4), 256, 0, stream>>>(P);
    transpose_v<<<dim3(32, 16, 4), 256, 0, stream>>>(vb, vt);
    pv_gemm<<<dim3(8, 16, 4), 256, 0, stream>>>(P, vt, out);
}

// Round 2
// 204.117 us; speedup vs baseline: 1.2754x; 1.2754x over previous
//
#include <hip/hip_runtime.h>
#include <hip/hip_bf16.h>

typedef unsigned int uint32;
typedef unsigned short ushort_t;

typedef __bf16 bf16x8 __attribute__((ext_vector_type(8)));
typedef float f32x4 __attribute__((ext_vector_type(4)));

// fp32 -> bf16 round-to-nearest-even (finite inputs only)
__device__ __forceinline__ ushort_t f2bf(float f) {
    uint32 u = __float_as_uint(f);
    u += 0x7fffu + ((u >> 16) & 1u);
    return (ushort_t)(u >> 16);
}
__device__ __forceinline__ float bf2f(ushort_t h) {
    return __uint_as_float(((uint32)h) << 16);
}

union U16 { int4 v; ushort_t u[8]; };

// async global->LDS, 16B per lane (m97 lever: compiler never auto-emits this)
__device__ __forceinline__ void gll16(const ushort_t* g, ushort_t* l) {
    __builtin_amdgcn_global_load_lds(
        (const __attribute__((address_space(1))) unsigned int*)g,
        (__attribute__((address_space(3))) unsigned int*)l, 16, 0, 0);
}

// ---------------------------------------------------------------------------
// m97 GEMM micro-structure: 128x128 tile, BK=32, 4 waves (2x2 of 64x64),
// linear LDS [128][32] bf16 (global_load_lds requires contiguous dest),
// mfma_f32_16x16x32_bf16. A,B both K-contiguous (gemm_bt form).
// ---------------------------------------------------------------------------
__device__ __forceinline__ void stage_tile(
    const ushort_t* __restrict__ A, int lda, int k0, ushort_t* As, int tid)
{
    // 128 rows x 32 cols bf16 = 8KB = 512 chunks of 16B; 2 per thread.
    // Within a wave, chunks are consecutive -> LDS dest = wave base + lane*16.
#pragma unroll
    for (int i = 0; i < 2; ++i) {
        int c = tid + 256 * i;
        gll16(&A[(size_t)(c >> 2) * lda + k0 + (c & 3) * 8], &As[c * 8]);
    }
}

__device__ __forceinline__ void mfma_tile(
    const ushort_t* As, const ushort_t* Bs, int lane, int wr, int wc,
    f32x4 acc[4][4])
{
    const int koff = (lane >> 4) * 8;
    bf16x8 a[4], bb[4];
#pragma unroll
    for (int m = 0; m < 4; ++m)
        a[m] = *(const bf16x8*)&As[(wr * 64 + m * 16 + (lane & 15)) * 32 + koff];
#pragma unroll
    for (int n = 0; n < 4; ++n)
        bb[n] = *(const bf16x8*)&Bs[(wc * 64 + n * 16 + (lane & 15)) * 32 + koff];
#pragma unroll
    for (int m = 0; m < 4; ++m)
#pragma unroll
        for (int n = 0; n < 4; ++n)
            acc[m][n] = __builtin_amdgcn_mfma_f32_16x16x32_bf16(a[m], bb[n], acc[m][n], 0, 0, 0);
}

// epilogue: verified C/D layout col=lane&15, row=(lane>>4)*4+j
__device__ __forceinline__ void store_tile_bf16(
    ushort_t* __restrict__ Dst, int ldd, int tid, const f32x4 acc[4][4], float scale)
{
    const int lane = tid & 63, wid = tid >> 6;
    const int wr = wid >> 1, wc = wid & 1;
#pragma unroll
    for (int m = 0; m < 4; ++m)
#pragma unroll
        for (int n = 0; n < 4; ++n)
#pragma unroll
            for (int j = 0; j < 4; ++j) {
                int row = wr * 64 + m * 16 + (lane >> 4) * 4 + j;
                int col = wc * 64 + n * 16 + (lane & 15);
                Dst[(size_t)row * ldd + col] = f2bf(acc[m][n][j] * scale);
            }
}

// ---------------------------------------------------------------------------
// Kernel 0a: X fp32 -> bf16. 8M elems, 8/thread.
// ---------------------------------------------------------------------------
__global__ __launch_bounds__(256) void conv_x(
    const float* __restrict__ X, ushort_t* __restrict__ Xb)
{
    size_t t = (size_t)blockIdx.x * 256 + threadIdx.x;
    size_t base = t * 8;
    float4 f0 = *(const float4*)&X[base];
    float4 f1 = *(const float4*)&X[base + 4];
    U16 o;
    o.u[0] = f2bf(f0.x); o.u[1] = f2bf(f0.y); o.u[2] = f2bf(f0.z); o.u[3] = f2bf(f0.w);
    o.u[4] = f2bf(f1.x); o.u[5] = f2bf(f1.y); o.u[6] = f2bf(f1.z); o.u[7] = f2bf(f1.w);
    *(int4*)&Xb[base] = o.v;
}

// ---------------------------------------------------------------------------
// Kernel 0b: Wq|Wk|Wv fp32 -> concatenated bf16 [3072][1024].
// ---------------------------------------------------------------------------
__global__ __launch_bounds__(256) void conv_w(
    const float* __restrict__ Wq, const float* __restrict__ Wk,
    const float* __restrict__ Wv, ushort_t* __restrict__ Wb)
{
    size_t t = (size_t)blockIdx.x * 256 + threadIdx.x;
    size_t base = t * 8;                  // < 3*1048576
    int z = (int)(base >> 20);
    size_t off = base & ((1u << 20) - 1);
    const float* W = (z == 0) ? Wq : ((z == 1) ? Wk : Wv);
    float4 f0 = *(const float4*)&W[off];
    float4 f1 = *(const float4*)&W[off + 4];
    U16 o;
    o.u[0] = f2bf(f0.x); o.u[1] = f2bf(f0.y); o.u[2] = f2bf(f0.z); o.u[3] = f2bf(f0.w);
    o.u[4] = f2bf(f1.x); o.u[5] = f2bf(f1.y); o.u[6] = f2bf(f1.z); o.u[7] = f2bf(f1.w);
    *(int4*)&Wb[base] = o.v;
}

// ---------------------------------------------------------------------------
// Kernel 1: QKV projection, all-bf16, m97 structure.
// Xb [8192][1024], Wb [3072][1024] -> QKV bf16 3x[8192][1024].
// grid (24, 64): bn covers 3072/128; z = bn/8 selects q/k/v slice.
// ---------------------------------------------------------------------------
__global__ __launch_bounds__(256) void qkv_gemm(
    const ushort_t* __restrict__ Xb, const ushort_t* __restrict__ Wb,
    ushort_t* __restrict__ QKV)
{
    const int bm = blockIdx.y, bn = blockIdx.x;
    const int tid = threadIdx.x;
    __shared__ __align__(16) ushort_t As[128 * 32];
    __shared__ __align__(16) ushort_t Bs[128 * 32];
    const ushort_t* A = Xb + (size_t)bm * 128 * 1024;
    const ushort_t* Bm = Wb + (size_t)bn * 128 * 1024;
    const int lane = tid & 63, wid = tid >> 6;
    const int wr = wid >> 1, wc = wid & 1;
    f32x4 acc[4][4] = {};
    for (int k0 = 0; k0 < 1024; k0 += 32) {
        stage_tile(A, 1024, k0, As, tid);
        stage_tile(Bm, 1024, k0, Bs, tid);
        __syncthreads();
        mfma_tile(As, Bs, lane, wr, wc, acc);
        __syncthreads();
    }
    const int z = bn >> 3;
    ushort_t* Dst = QKV + (size_t)z * 8192 * 1024
                  + (size_t)bm * 128 * 1024 + (bn & 7) * 128;
    store_tile_bf16(Dst, 1024, tid, acc, 1.0f);
}

// ---------------------------------------------------------------------------
// Kernel 2: scores S = (Q @ K^T) / 32, bf16 out. Causal block-skip (bn > bm).
// grid (16,16,4). Masking deferred to softmax (by index).
// ---------------------------------------------------------------------------
__global__ __launch_bounds__(256) void scores_gemm(
    const ushort_t* __restrict__ Q, const ushort_t* __restrict__ Kb,
    ushort_t* __restrict__ P)
{
    const int b = blockIdx.z;
    const int bm = blockIdx.y, bn = blockIdx.x;
    if (bn > bm) return;  // fully masked tile
    const int tid = threadIdx.x;
    __shared__ __align__(16) ushort_t As[128 * 32];
    __shared__ __align__(16) ushort_t Bs[128 * 32];
    const ushort_t* A = Q + (size_t)b * 2048 * 1024 + (size_t)bm * 128 * 1024;
    const ushort_t* Bm = Kb + (size_t)b * 2048 * 1024 + (size_t)bn * 128 * 1024;
    const int lane = tid & 63, wid = tid >> 6;
    const int wr = wid >> 1, wc = wid & 1;
    f32x4 acc[4][4] = {};
    for (int k0 = 0; k0 < 1024; k0 += 32) {
        stage_tile(A, 1024, k0, As, tid);
        stage_tile(Bm, 1024, k0, Bs, tid);
        __syncthreads();
        mfma_tile(As, Bs, lane, wr, wc, acc);
        __syncthreads();
    }
    ushort_t* Pb = P + (size_t)b * 2048 * 2048 + (size_t)bm * 128 * 2048 + bn * 128;
    store_tile_bf16(Pb, 2048, tid, acc, 0.03125f);  // 1/sqrt(1024)
}

// ---------------------------------------------------------------------------
// Kernel 3: row softmax in place on P (bf16), causal mask by index.
// Writes exact 0 for masked entries -> PV reads a fully defined buffer.
// grid (2048, 4), 256 threads, 8 elems/thread.
// ---------------------------------------------------------------------------
__global__ __launch_bounds__(256) void softmax_rows(ushort_t* __restrict__ P)
{
    const int q = blockIdx.x, b = blockIdx.y;
    ushort_t* row = P + ((size_t)b * 2048 + q) * 2048;
    const int tid = threadIdx.x;
    U16 in;
    in.v = *(const int4*)&row[tid * 8];
    float v[8];
    float m = -3.0e38f;
#pragma unroll
    for (int j = 0; j < 8; ++j) {
        int k = tid * 8 + j;
        float s = bf2f(in.u[j]);
        v[j] = (k <= q) ? s : -3.0e38f;
        m = fmaxf(m, v[j]);
    }
#pragma unroll
    for (int off = 32; off >= 1; off >>= 1) m = fmaxf(m, __shfl_xor(m, off));
    __shared__ float red[4];
    if ((tid & 63) == 0) red[tid >> 6] = m;
    __syncthreads();
    m = fmaxf(fmaxf(red[0], red[1]), fmaxf(red[2], red[3]));
    float e[8], s = 0.f;
#pragma unroll
    for (int j = 0; j < 8; ++j) {
        e[j] = (v[j] > -1.0e38f) ? __expf(v[j] - m) : 0.f;
        s += e[j];
    }
#pragma unroll
    for (int off = 32; off >= 1; off >>= 1) s += __shfl_xor(s, off);
    __syncthreads();  // red reuse
    if ((tid & 63) == 0) red[tid >> 6] = s;
    __syncthreads();
    s = red[0] + red[1] + red[2] + red[3];
    float inv = 1.f / s;
    U16 outv;
#pragma unroll
    for (int j = 0; j < 8; ++j) outv.u[j] = f2bf(e[j] * inv);
    *(int4*)&row[tid * 8] = outv.v;
}

// ---------------------------------------------------------------------------
// Kernel 4: V transpose per batch: Vt[b][d][k] = V[b][k][d]. 64x64 LDS tiles.
// grid (32, 16, 4).
// ---------------------------------------------------------------------------
__global__ __launch_bounds__(256) void transpose_v(
    const ushort_t* __restrict__ V, ushort_t* __restrict__ Vt)
{
    __shared__ ushort_t ts[64][72];
    const int b = blockIdx.z;
    const ushort_t* Vb = V + (size_t)b * 2048 * 1024;
    ushort_t* Vtb = Vt + (size_t)b * 1024 * 2048;
    const int k0 = blockIdx.x * 64, d0 = blockIdx.y * 64;
    const int tid = threadIdx.x;
#pragma unroll
    for (int i = 0; i < 2; ++i) {
        int c = tid + 256 * i;
        int row = c >> 3, col8 = c & 7;
        U16 vv;
        vv.v = *(const int4*)&Vb[(size_t)(k0 + row) * 1024 + d0 + col8 * 8];
#pragma unroll
        for (int j = 0; j < 8; ++j) ts[row][col8 * 8 + j] = vv.u[j];
    }
    __syncthreads();
#pragma unroll
    for (int i = 0; i < 2; ++i) {
        int c = tid + 256 * i;
        int drow = c >> 3, kcol8 = c & 7;
        U16 vv;
#pragma unroll
        for (int j = 0; j < 8; ++j) vv.u[j] = ts[kcol8 * 8 + j][drow];
        *(int4*)&Vtb[(size_t)(d0 + drow) * 2048 + k0 + kcol8 * 8] = vv.v;
    }
}

// ---------------------------------------------------------------------------
// Kernel 5: O = P @ V  via Vt (gemm_bt). K capped at diagonal. fp32 out.
// grid (8, 16, 4).
// ---------------------------------------------------------------------------
__global__ __launch_bounds__(256) void pv_gemm(
    const ushort_t* __restrict__ P, const ushort_t* __restrict__ Vt,
    float* __restrict__ O)
{
    const int b = blockIdx.z;
    const int bm = blockIdx.y;  // q tile
    const int bn = blockIdx.x;  // d tile
    const int tid = threadIdx.x;
    __shared__ __align__(16) ushort_t As[128 * 32];
    __shared__ __align__(16) ushort_t Bs[128 * 32];
    const ushort_t* A = P + (size_t)b * 2048 * 2048 + (size_t)bm * 128 * 2048;
    const ushort_t* Bm = Vt + (size_t)b * 1024 * 2048 + (size_t)bn * 128 * 2048;
    const int lane = tid & 63, wid = tid >> 6;
    const int wr = wid >> 1, wc = wid & 1;
    f32x4 acc[4][4] = {};
    const int kEnd = (bm + 1) * 128;  // P[q][k]=0 beyond diagonal
    for (int k0 = 0; k0 < kEnd; k0 += 32) {
        stage_tile(A, 2048, k0, As, tid);
        stage_tile(Bm, 2048, k0, Bs, tid);
        __syncthreads();
        mfma_tile(As, Bs, lane, wr, wc, acc);
        __syncthreads();
    }
    float* Ob = O + (size_t)b * 2048 * 1024 + (size_t)bm * 128 * 1024 + bn * 128;
#pragma unroll
    for (int m = 0; m < 4; ++m)
#pragma unroll
        for (int n = 0; n < 4; ++n)
#pragma unroll
            for (int j = 0; j < 4; ++j) {
                int row = wr * 64 + m * 16 + (lane >> 4) * 4 + j;
                int col = wc * 64 + n * 16 + (lane & 15);
                Ob[(size_t)row * 1024 + col] = acc[m][n][j];
            }
}

// ---------------------------------------------------------------------------
// Workspace layout (bf16 elems), total 48M elems = 96 MB (round-1-proven):
//   phase 1:  Xb [8192][1024] @ 0        (8M)   -- dead after qkv
//             Wb [3072][1024] @ 8M       (3M)   -- dead after qkv
//   phase 2+: P  [4][2048][2048] @ 0     (16M)  -- aliases Xb/Wb (sequential)
//   q  @ 16M, k @ 24M, v @ 32M, vt @ 40M (8M each)
// ---------------------------------------------------------------------------
extern "C" void kernel_launch(void* const* d_in, const int* in_sizes, int n_in,
                              void* d_out, int out_size, void* d_ws, size_t ws_size,
                              hipStream_t stream) {
    const float* x  = (const float*)d_in[0];
    const float* Wq = (const float*)d_in[1];
    const float* Wk = (const float*)d_in[2];
    const float* Wv = (const float*)d_in[3];
    float* out = (float*)d_out;
    ushort_t* ws = (ushort_t*)d_ws;
    ushort_t* Xb = ws;                               // aliases P (phase 1 only)
    ushort_t* Wb = ws + (size_t)8192 * 1024;
    ushort_t* P  = ws;
    ushort_t* qb = ws + (size_t)16 * 1024 * 1024;
    ushort_t* kb = qb + (size_t)8192 * 1024;
    ushort_t* vb = kb + (size_t)8192 * 1024;
    ushort_t* vt = vb + (size_t)8192 * 1024;

    conv_x<<<dim3(4096), 256, 0, stream>>>(x, Xb);
    conv_w<<<dim3(1536), 256, 0, stream>>>(Wq, Wk, Wv, Wb);
    qkv_gemm<<<dim3(24, 64), 256, 0, stream>>>(Xb, Wb, qb);
    scores_gemm<<<dim3(16, 16, 4), 256, 0, stream>>>(qb, kb, P);
    softmax_rows<<<dim3(2048, 4), 256, 0, stream>>>(P);
    transpose_v<<<dim3(32, 16, 4), 256, 0, stream>>>(vb, vt);
    pv_gemm<<<dim3(8, 16, 4), 256, 0, stream>>>(P, vt, out);
}

// Round 4
// 198.189 us; speedup vs baseline: 1.3135x; 1.0299x over previous
//
#include <hip/hip_runtime.h>
#include <hip/hip_bf16.h>

typedef unsigned int uint32;
typedef unsigned short ushort_t;

typedef __bf16 bf16x8 __attribute__((ext_vector_type(8)));
typedef float f32x4 __attribute__((ext_vector_type(4)));

__device__ __forceinline__ ushort_t f2bf(float f) {
    uint32 u = __float_as_uint(f);
    u += 0x7fffu + ((u >> 16) & 1u);
    return (ushort_t)(u >> 16);
}
__device__ __forceinline__ float bf2f(ushort_t h) {
    return __uint_as_float(((uint32)h) << 16);
}

union U16 { int4 v; ushort_t u[8]; };

// async global->LDS, 16B per lane (dest = wave-uniform base + lane*16)
__device__ __forceinline__ void gll16(const ushort_t* g, ushort_t* l) {
    __builtin_amdgcn_global_load_lds(
        (const __attribute__((address_space(1))) unsigned int*)g,
        (__attribute__((address_space(3))) unsigned int*)l, 16, 0, 0);
}

#define SBAR() __builtin_amdgcn_s_barrier()
#define LGKM0() asm volatile("s_waitcnt lgkmcnt(0)" ::: "memory")
#define VM0()   asm volatile("s_waitcnt vmcnt(0)" ::: "memory")

// ===========================================================================
// 256x256 GEMM, BK=64, 512 thr = 8 waves (2M x 4N), wave tile 128x64.
// LDS 128KB = 2buf x {A,B} x 2half x [128][64] bf16.
// Double-buffer discipline (race-free, 2-buffer invariant):
//   during ktile t, stage ALL of tile t+1 (into buf^1) in phases 0-1;
//   vmcnt(0) at the tile boundary (issue-to-drain ~3 phases hides latency).
// st_16x32 swizzle on ds_read; staging pre-swizzles the global source column
// so LDS dest stays linear (rule #21).
// ===========================================================================
__device__ __forceinline__ int lds_off(int buf, int op, int half) {
    return ((((buf << 1) | op) << 1) | half) * 8192;  // ushort units
}
__device__ __forceinline__ int frag_off(int r, int k) {
    return r * 64 + (k ^ (((r >> 2) & 1) << 4));
}

// stage global half-tile #g (per K-tile: g&3 = A0,A1,B0,B1); 2 gll16/thread
__device__ __forceinline__ void stage_g(
    const ushort_t* __restrict__ A, int lda,
    const ushort_t* __restrict__ B, int ldb,
    ushort_t* lds, int g, int c)
{
    int gt = g >> 2;
    int op = (g >> 1) & 1, half = g & 1;
    const ushort_t* G = op ? B : A;
    int ldg = op ? ldb : lda;
    ushort_t* L = lds + lds_off(gt & 1, op, half);
    const ushort_t* Gb = G + (size_t)(half * 128) * ldg + gt * 64;
#pragma unroll
    for (int i = 0; i < 2; ++i) {
        int chunk = i * 512 + c;                       // 0..1023, 16B each
        int row = chunk >> 3, col8 = chunk & 7;
        int scol8 = col8 ^ (((row >> 2) & 1) << 1);    // inverse swizzle on src
        gll16(&Gb[(size_t)row * ldg + scol8 * 8], &L[chunk * 8]);
    }
}

__device__ __forceinline__ void ktile256(
    const ushort_t* __restrict__ A, int lda,
    const ushort_t* __restrict__ B, int ldb,
    ushort_t* lds, int t, int NT, int c, int lane, int wm, int wn,
    f32x4 acc[8][4])
{
    const int buf = t & 1;
    const ushort_t* Ab = lds + lds_off(buf, 0, wm);
    const ushort_t* Bb = lds + lds_off(buf, 1, wn >> 1);
    const int rB = (wn & 1) * 64;
    const int l15 = lane & 15;
    const int kk = (lane >> 4) * 8;
    const bool pre = (t + 1 < NT);
    const int g0 = 4 * (t + 1);
    bf16x8 a4[4][2], bLo[2][2], bHi[2][2];

    // ---- phase 0: quadrant (m0..3, n0..1); stage A-halves of tile t+1
#pragma unroll
    for (int m = 0; m < 4; ++m)
#pragma unroll
        for (int ks = 0; ks < 2; ++ks)
            a4[m][ks] = *(const bf16x8*)&Ab[frag_off(m * 16 + l15, ks * 32 + kk)];
#pragma unroll
    for (int n = 0; n < 2; ++n)
#pragma unroll
        for (int ks = 0; ks < 2; ++ks)
            bLo[n][ks] = *(const bf16x8*)&Bb[frag_off(rB + n * 16 + l15, ks * 32 + kk)];
    if (pre) { stage_g(A, lda, B, ldb, lds, g0 + 0, c);
               stage_g(A, lda, B, ldb, lds, g0 + 1, c); }
    SBAR(); LGKM0();
    __builtin_amdgcn_s_setprio(1);
#pragma unroll
    for (int m = 0; m < 4; ++m)
#pragma unroll
        for (int n = 0; n < 2; ++n)
#pragma unroll
            for (int ks = 0; ks < 2; ++ks)
                acc[m][n] = __builtin_amdgcn_mfma_f32_16x16x32_bf16(a4[m][ks], bLo[n][ks], acc[m][n], 0, 0, 0);
    __builtin_amdgcn_s_setprio(0);
    SBAR();

    // ---- phase 1: (m0..3, n2..3); stage B-halves of tile t+1
#pragma unroll
    for (int n = 0; n < 2; ++n)
#pragma unroll
        for (int ks = 0; ks < 2; ++ks)
            bHi[n][ks] = *(const bf16x8*)&Bb[frag_off(rB + (n + 2) * 16 + l15, ks * 32 + kk)];
    if (pre) { stage_g(A, lda, B, ldb, lds, g0 + 2, c);
               stage_g(A, lda, B, ldb, lds, g0 + 3, c); }
    SBAR(); LGKM0();
    __builtin_amdgcn_s_setprio(1);
#pragma unroll
    for (int m = 0; m < 4; ++m)
#pragma unroll
        for (int n = 0; n < 2; ++n)
#pragma unroll
            for (int ks = 0; ks < 2; ++ks)
                acc[m][n + 2] = __builtin_amdgcn_mfma_f32_16x16x32_bf16(a4[m][ks], bHi[n][ks], acc[m][n + 2], 0, 0, 0);
    __builtin_amdgcn_s_setprio(0);
    SBAR();

    // ---- phase 2: (m4..7, n2..3) — reload A rows 64..127
#pragma unroll
    for (int m = 0; m < 4; ++m)
#pragma unroll
        for (int ks = 0; ks < 2; ++ks)
            a4[m][ks] = *(const bf16x8*)&Ab[frag_off((m + 4) * 16 + l15, ks * 32 + kk)];
    SBAR(); LGKM0();
    __builtin_amdgcn_s_setprio(1);
#pragma unroll
    for (int m = 0; m < 4; ++m)
#pragma unroll
        for (int n = 0; n < 2; ++n)
#pragma unroll
            for (int ks = 0; ks < 2; ++ks)
                acc[m + 4][n + 2] = __builtin_amdgcn_mfma_f32_16x16x32_bf16(a4[m][ks], bHi[n][ks], acc[m + 4][n + 2], 0, 0, 0);
    __builtin_amdgcn_s_setprio(0);
    SBAR();

    // ---- phase 3: (m4..7, n0..1) — register-only (bLo, a4 retained)
    __builtin_amdgcn_s_setprio(1);
#pragma unroll
    for (int m = 0; m < 4; ++m)
#pragma unroll
        for (int n = 0; n < 2; ++n)
#pragma unroll
            for (int ks = 0; ks < 2; ++ks)
                acc[m + 4][n] = __builtin_amdgcn_mfma_f32_16x16x32_bf16(a4[m][ks], bLo[n][ks], acc[m + 4][n], 0, 0, 0);
    __builtin_amdgcn_s_setprio(0);
    if (pre) VM0();   // tile t+1 fully landed (per-wave; barrier makes it collective)
    SBAR();
}

__device__ __forceinline__ void gemm256(
    const ushort_t* __restrict__ A, int lda,
    const ushort_t* __restrict__ B, int ldb,
    ushort_t* lds, int NT, f32x4 acc[8][4])
{
    const int c = threadIdx.x;
    const int lane = c & 63, wid = c >> 6;
    const int wm = wid >> 2, wn = wid & 3;
#pragma unroll
    for (int g = 0; g < 4; ++g) stage_g(A, lda, B, ldb, lds, g, c);  // tile 0
    VM0();
    SBAR();
    for (int t = 0; t < NT; ++t)
        ktile256(A, lda, B, ldb, lds, t, NT, c, lane, wm, wn, acc);
}

// ---------------------------------------------------------------------------
// Kernel 0a/0b: fp32 -> bf16 converts
// ---------------------------------------------------------------------------
__global__ __launch_bounds__(256) void conv_x(
    const float* __restrict__ X, ushort_t* __restrict__ Xb)
{
    size_t t = (size_t)blockIdx.x * 256 + threadIdx.x;
    size_t base = t * 8;
    float4 f0 = *(const float4*)&X[base];
    float4 f1 = *(const float4*)&X[base + 4];
    U16 o;
    o.u[0] = f2bf(f0.x); o.u[1] = f2bf(f0.y); o.u[2] = f2bf(f0.z); o.u[3] = f2bf(f0.w);
    o.u[4] = f2bf(f1.x); o.u[5] = f2bf(f1.y); o.u[6] = f2bf(f1.z); o.u[7] = f2bf(f1.w);
    *(int4*)&Xb[base] = o.v;
}

__global__ __launch_bounds__(256) void conv_w(
    const float* __restrict__ Wq, const float* __restrict__ Wk,
    const float* __restrict__ Wv, ushort_t* __restrict__ Wb)
{
    size_t t = (size_t)blockIdx.x * 256 + threadIdx.x;
    size_t base = t * 8;
    int z = (int)(base >> 20);
    size_t off = base & ((1u << 20) - 1);
    const float* W = (z == 0) ? Wq : ((z == 1) ? Wk : Wv);
    float4 f0 = *(const float4*)&W[off];
    float4 f1 = *(const float4*)&W[off + 4];
    U16 o;
    o.u[0] = f2bf(f0.x); o.u[1] = f2bf(f0.y); o.u[2] = f2bf(f0.z); o.u[3] = f2bf(f0.w);
    o.u[4] = f2bf(f1.x); o.u[5] = f2bf(f1.y); o.u[6] = f2bf(f1.z); o.u[7] = f2bf(f1.w);
    *(int4*)&Wb[base] = o.v;
}

// ---------------------------------------------------------------------------
// Kernel 1: QKV projection, 256^2. grid (12, 32).
// ---------------------------------------------------------------------------
__global__ __launch_bounds__(512, 2) void qkv_gemm256(
    const ushort_t* __restrict__ Xb, const ushort_t* __restrict__ Wb,
    ushort_t* __restrict__ QKV)
{
    __shared__ __align__(16) ushort_t lds[65536];  // 128 KB
    const int bm = blockIdx.y, bn = blockIdx.x;
    f32x4 acc[8][4] = {};
    gemm256(Xb + (size_t)bm * 256 * 1024, 1024,
            Wb + (size_t)bn * 256 * 1024, 1024, lds, 16, acc);
    const int z = bn >> 2;
    ushort_t* Dst = QKV + (size_t)z * 8192 * 1024
                  + (size_t)bm * 256 * 1024 + (bn & 3) * 256;
    const int tid = threadIdx.x, lane = tid & 63, wid = tid >> 6;
    const int wm = wid >> 2, wn = wid & 3;
#pragma unroll
    for (int m = 0; m < 8; ++m)
#pragma unroll
        for (int n = 0; n < 4; ++n)
#pragma unroll
            for (int j = 0; j < 4; ++j) {
                int row = wm * 128 + m * 16 + (lane >> 4) * 4 + j;
                int col = wn * 64 + n * 16 + (lane & 15);
                Dst[(size_t)row * 1024 + col] = f2bf(acc[m][n][j]);
            }
}

// ---------------------------------------------------------------------------
// Kernel 2: scores = (Q @ K^T)/32, 256^2, causal block-skip. grid (8, 8, 4).
// ---------------------------------------------------------------------------
__global__ __launch_bounds__(512, 2) void scores_gemm256(
    const ushort_t* __restrict__ Q, const ushort_t* __restrict__ Kb,
    ushort_t* __restrict__ P)
{
    const int b = blockIdx.z, bm = blockIdx.y, bn = blockIdx.x;
    if (bn > bm) return;
    __shared__ __align__(16) ushort_t lds[65536];
    f32x4 acc[8][4] = {};
    gemm256(Q  + (size_t)b * 2048 * 1024 + (size_t)bm * 256 * 1024, 1024,
            Kb + (size_t)b * 2048 * 1024 + (size_t)bn * 256 * 1024, 1024,
            lds, 16, acc);
    ushort_t* Pb = P + (size_t)b * 2048 * 2048 + (size_t)bm * 256 * 2048 + bn * 256;
    const int tid = threadIdx.x, lane = tid & 63, wid = tid >> 6;
    const int wm = wid >> 2, wn = wid & 3;
#pragma unroll
    for (int m = 0; m < 8; ++m)
#pragma unroll
        for (int n = 0; n < 4; ++n)
#pragma unroll
            for (int j = 0; j < 4; ++j) {
                int row = wm * 128 + m * 16 + (lane >> 4) * 4 + j;
                int col = wn * 64 + n * 16 + (lane & 15);
                Pb[(size_t)row * 2048 + col] = f2bf(acc[m][n][j] * 0.03125f);
            }
}

// ---------------------------------------------------------------------------
// Kernel 3: row softmax in place on P (bf16), causal by index.
// Only touches k < kmax = ((q>>7)+1)*128 — pv never reads beyond.
// ---------------------------------------------------------------------------
__global__ __launch_bounds__(256) void softmax_rows(ushort_t* __restrict__ P)
{
    const int q = blockIdx.x, b = blockIdx.y;
    ushort_t* row = P + ((size_t)b * 2048 + q) * 2048;
    const int tid = threadIdx.x;
    const int kmax = ((q >> 7) + 1) * 128;
    const bool active = tid * 8 < kmax;
    float v[8];
    float m = -3.0e38f;
    if (active) {
        U16 in;
        in.v = *(const int4*)&row[tid * 8];
#pragma unroll
        for (int j = 0; j < 8; ++j) {
            int k = tid * 8 + j;
            float s = bf2f(in.u[j]);
            v[j] = (k <= q) ? s : -3.0e38f;
            m = fmaxf(m, v[j]);
        }
    } else {
#pragma unroll
        for (int j = 0; j < 8; ++j) v[j] = -3.0e38f;
    }
#pragma unroll
    for (int off = 32; off >= 1; off >>= 1) m = fmaxf(m, __shfl_xor(m, off));
    __shared__ float red[4];
    if ((tid & 63) == 0) red[tid >> 6] = m;
    __syncthreads();
    m = fmaxf(fmaxf(red[0], red[1]), fmaxf(red[2], red[3]));
    float e[8], s = 0.f;
#pragma unroll
    for (int j = 0; j < 8; ++j) {
        e[j] = (v[j] > -1.0e38f) ? __expf(v[j] - m) : 0.f;
        s += e[j];
    }
#pragma unroll
    for (int off = 32; off >= 1; off >>= 1) s += __shfl_xor(s, off);
    __syncthreads();
    if ((tid & 63) == 0) red[tid >> 6] = s;
    __syncthreads();
    s = red[0] + red[1] + red[2] + red[3];
    float inv = 1.f / s;
    if (active) {
        U16 outv;
#pragma unroll
        for (int j = 0; j < 8; ++j) outv.u[j] = f2bf(e[j] * inv);
        *(int4*)&row[tid * 8] = outv.v;
    }
}

// ---------------------------------------------------------------------------
// Kernel 4: V transpose per batch. grid (32, 16, 4).
// ---------------------------------------------------------------------------
__global__ __launch_bounds__(256) void transpose_v(
    const ushort_t* __restrict__ V, ushort_t* __restrict__ Vt)
{
    __shared__ ushort_t ts[64][72];
    const int b = blockIdx.z;
    const ushort_t* Vb = V + (size_t)b * 2048 * 1024;
    ushort_t* Vtb = Vt + (size_t)b * 1024 * 2048;
    const int k0 = blockIdx.x * 64, d0 = blockIdx.y * 64;
    const int tid = threadIdx.x;
#pragma unroll
    for (int i = 0; i < 2; ++i) {
        int c = tid + 256 * i;
        int row = c >> 3, col8 = c & 7;
        U16 vv;
        vv.v = *(const int4*)&Vb[(size_t)(k0 + row) * 1024 + d0 + col8 * 8];
#pragma unroll
        for (int j = 0; j < 8; ++j) ts[row][col8 * 8 + j] = vv.u[j];
    }
    __syncthreads();
#pragma unroll
    for (int i = 0; i < 2; ++i) {
        int c = tid + 256 * i;
        int drow = c >> 3, kcol8 = c & 7;
        U16 vv;
#pragma unroll
        for (int j = 0; j < 8; ++j) vv.u[j] = ts[kcol8 * 8 + j][drow];
        *(int4*)&Vtb[(size_t)(d0 + drow) * 2048 + k0 + kcol8 * 8] = vv.v;
    }
}

// ---------------------------------------------------------------------------
// Kernel 5: O = P @ V via Vt, m97-128^2, K capped at diagonal, heavy-first.
// grid (8, 16, 4); bm = 15 - blockIdx.y so K=2048 blocks dispatch first.
// ---------------------------------------------------------------------------
__device__ __forceinline__ void stage_tile(
    const ushort_t* __restrict__ A, int lda, int k0, ushort_t* As, int tid)
{
#pragma unroll
    for (int i = 0; i < 2; ++i) {
        int c = tid + 256 * i;
        gll16(&A[(size_t)(c >> 2) * lda + k0 + (c & 3) * 8], &As[c * 8]);
    }
}

__global__ __launch_bounds__(256) void pv_gemm(
    const ushort_t* __restrict__ P, const ushort_t* __restrict__ Vt,
    float* __restrict__ O)
{
    const int b = blockIdx.z;
    const int bm = 15 - blockIdx.y;  // heavy (K=2048) blocks first
    const int bn = blockIdx.x;
    const int tid = threadIdx.x;
    __shared__ __align__(16) ushort_t As[128 * 32];
    __shared__ __align__(16) ushort_t Bs[128 * 32];
    const ushort_t* A = P + (size_t)b * 2048 * 2048 + (size_t)bm * 128 * 2048;
    const ushort_t* Bm = Vt + (size_t)b * 1024 * 2048 + (size_t)bn * 128 * 2048;
    const int lane = tid & 63, wid = tid >> 6;
    const int wr = wid >> 1, wc = wid & 1;
    f32x4 acc[4][4] = {};
    const int kEnd = (bm + 1) * 128;
    for (int k0 = 0; k0 < kEnd; k0 += 32) {
        stage_tile(A, 2048, k0, As, tid);
        stage_tile(Bm, 2048, k0, Bs, tid);
        __syncthreads();
        const int koff = (lane >> 4) * 8;
        bf16x8 a[4], bb[4];
#pragma unroll
        for (int m = 0; m < 4; ++m)
            a[m] = *(const bf16x8*)&As[(wr * 64 + m * 16 + (lane & 15)) * 32 + koff];
#pragma unroll
        for (int n = 0; n < 4; ++n)
            bb[n] = *(const bf16x8*)&Bs[(wc * 64 + n * 16 + (lane & 15)) * 32 + koff];
#pragma unroll
        for (int m = 0; m < 4; ++m)
#pragma unroll
            for (int n = 0; n < 4; ++n)
                acc[m][n] = __builtin_amdgcn_mfma_f32_16x16x32_bf16(a[m], bb[n], acc[m][n], 0, 0, 0);
        __syncthreads();
    }
    float* Ob = O + (size_t)b * 2048 * 1024 + (size_t)bm * 128 * 1024 + bn * 128;
#pragma unroll
    for (int m = 0; m < 4; ++m)
#pragma unroll
        for (int n = 0; n < 4; ++n)
#pragma unroll
            for (int j = 0; j < 4; ++j) {
                int row = wr * 64 + m * 16 + (lane >> 4) * 4 + j;
                int col = wc * 64 + n * 16 + (lane & 15);
                Ob[(size_t)row * 1024 + col] = acc[m][n][j];
            }
}

// ---------------------------------------------------------------------------
// Workspace (bf16 elems), 48M total:
//   phase 1: Xb [8192][1024] @0 (8M), Wb [3072][1024] @8M (3M) -- dead after qkv
//   phase 2: P [4][2048][2048] @0 (16M, aliases Xb/Wb)
//   q @16M, k @24M, v @32M, vt @40M
// ---------------------------------------------------------------------------
extern "C" void kernel_launch(void* const* d_in, const int* in_sizes, int n_in,
                              void* d_out, int out_size, void* d_ws, size_t ws_size,
                              hipStream_t stream) {
    const float* x  = (const float*)d_in[0];
    const float* Wq = (const float*)d_in[1];
    const float* Wk = (const float*)d_in[2];
    const float* Wv = (const float*)d_in[3];
    float* out = (float*)d_out;
    ushort_t* ws = (ushort_t*)d_ws;
    ushort_t* Xb = ws;
    ushort_t* Wb = ws + (size_t)8192 * 1024;
    ushort_t* P  = ws;
    ushort_t* qb = ws + (size_t)16 * 1024 * 1024;
    ushort_t* kb = qb + (size_t)8192 * 1024;
    ushort_t* vb = kb + (size_t)8192 * 1024;
    ushort_t* vt = vb + (size_t)8192 * 1024;

    conv_x<<<dim3(4096), 256, 0, stream>>>(x, Xb);
    conv_w<<<dim3(1536), 256, 0, stream>>>(Wq, Wk, Wv, Wb);
    qkv_gemm256<<<dim3(12, 32), 512, 0, stream>>>(Xb, Wb, qb);
    scores_gemm256<<<dim3(8, 8, 4), 512, 0, stream>>>(qb, kb, P);
    softmax_rows<<<dim3(2048, 4), 256, 0, stream>>>(P);
    transpose_v<<<dim3(32, 16, 4), 256, 0, stream>>>(vb, vt);
    pv_gemm<<<dim3(8, 16, 4), 256, 0, stream>>>(P, vt, out);
}

// Round 5
// 188.174 us; speedup vs baseline: 1.3835x; 1.0532x over previous
//
#include <hip/hip_runtime.h>
#include <hip/hip_bf16.h>

typedef unsigned int uint32;
typedef unsigned short ushort_t;

typedef __bf16 bf16x8 __attribute__((ext_vector_type(8)));
typedef float f32x4 __attribute__((ext_vector_type(4)));

__device__ __forceinline__ ushort_t f2bf(float f) {
    uint32 u = __float_as_uint(f);
    u += 0x7fffu + ((u >> 16) & 1u);
    return (ushort_t)(u >> 16);
}
__device__ __forceinline__ float bf2f(ushort_t h) {
    return __uint_as_float(((uint32)h) << 16);
}

union U16 { int4 v; ushort_t u[8]; };

// async global->LDS, 16B per lane (dest = wave-uniform base + lane*16)
__device__ __forceinline__ void gll16(const ushort_t* g, ushort_t* l) {
    __builtin_amdgcn_global_load_lds(
        (const __attribute__((address_space(1))) unsigned int*)g,
        (__attribute__((address_space(3))) unsigned int*)l, 16, 0, 0);
}

#define SBAR() __builtin_amdgcn_s_barrier()
#define LGKM0() asm volatile("s_waitcnt lgkmcnt(0)" ::: "memory")
#define VM0()   asm volatile("s_waitcnt vmcnt(0)" ::: "memory")
#define VM6()   asm volatile("s_waitcnt vmcnt(6)" ::: "memory")

// ===========================================================================
// 256x256 GEMM, BK=64, 512 thr = 8 waves (2M x 4N), wave tile 128x64.
// LDS 128KB = 2buf x {A,B} x 2half x [128][64] bf16.
//
// Swizzle (3-bit, bank-conflict-free): LDS row r keeps its 8 16B-slots
// permuted by slot ^= (r&7). Staging pre-permutes the global source column
// (LDS dest stays linear for global_load_lds, rule #21); ds_read applies the
// same XOR. 16 lanes reading one column-slot across 16 rows now spread over
// 8 slots = 32 banks, 2 lanes/bank (free).
//
// Counted-vmcnt double-buffer schedule (race-free; region overwrite only
// in a phase strictly after the region's last collective ds_read, which is
// barrier-separated):
//   reads of buf(t&1):  A-halves last read ph2, B-halves last read ph1.
//   tile t: ph0 stage (t+1):A1 | ph2 stage (t+2):B0,B1 | ph3 stage (t+2):A0
//   boundary: vmcnt(6) -> tile t+1 fully landed, 3 half-tiles of t+2 in
//   flight (issue-to-wait >= 4 phases, covers HBM latency).
// ===========================================================================
__device__ __forceinline__ int lds_off(int buf, int op, int half) {
    return ((((buf << 1) | op) << 1) | half) * 8192;  // ushort units
}
__device__ __forceinline__ int frag_off(int r, int k) {  // k multiple of 8
    return r * 64 + ((((k >> 3) ^ (r & 7))) << 3);
}

// stage half-tile h of K-tile X; h: 0=A-half0, 1=A-half1, 2=B-half0, 3=B-half1
__device__ __forceinline__ void stage_h(
    const ushort_t* __restrict__ A, int lda,
    const ushort_t* __restrict__ B, int ldb,
    ushort_t* lds, int X, int h, int c)
{
    int op = h >> 1, half = h & 1;
    const ushort_t* G = op ? B : A;
    int ldg = op ? ldb : lda;
    ushort_t* L = lds + lds_off(X & 1, op, half);
    const ushort_t* Gb = G + (size_t)(half * 128) * ldg + X * 64;
#pragma unroll
    for (int i = 0; i < 2; ++i) {
        int chunk = i * 512 + c;                 // 0..1023, 16B each
        int row = chunk >> 3, col8 = chunk & 7;
        int scol8 = col8 ^ (row & 7);            // inverse swizzle on source
        gll16(&Gb[(size_t)row * ldg + scol8 * 8], &L[chunk * 8]);
    }
}

__device__ __forceinline__ void ktile256(
    const ushort_t* __restrict__ A, int lda,
    const ushort_t* __restrict__ B, int ldb,
    ushort_t* lds, int t, int NT, int c, int lane, int wm, int wn,
    f32x4 acc[8][4])
{
    const int buf = t & 1;
    const ushort_t* Ab = lds + lds_off(buf, 0, wm);
    const ushort_t* Bb = lds + lds_off(buf, 1, wn >> 1);
    const int rB = (wn & 1) * 64;
    const int l15 = lane & 15;
    const int kk = (lane >> 4) * 8;
    const bool s1 = (t + 1 < NT);
    const bool s2 = (t + 2 < NT);
    bf16x8 a4[4][2], bLo[2][2], bHi[2][2];

    // ---- phase 0: quadrant (m0..3, n0..1); stage (t+1):A1
#pragma unroll
    for (int m = 0; m < 4; ++m)
#pragma unroll
        for (int ks = 0; ks < 2; ++ks)
            a4[m][ks] = *(const bf16x8*)&Ab[frag_off(m * 16 + l15, ks * 32 + kk)];
#pragma unroll
    for (int n = 0; n < 2; ++n)
#pragma unroll
        for (int ks = 0; ks < 2; ++ks)
            bLo[n][ks] = *(const bf16x8*)&Bb[frag_off(rB + n * 16 + l15, ks * 32 + kk)];
    if (s1) stage_h(A, lda, B, ldb, lds, t + 1, 1, c);
    SBAR(); LGKM0();
    __builtin_amdgcn_s_setprio(1);
#pragma unroll
    for (int m = 0; m < 4; ++m)
#pragma unroll
        for (int n = 0; n < 2; ++n)
#pragma unroll
            for (int ks = 0; ks < 2; ++ks)
                acc[m][n] = __builtin_amdgcn_mfma_f32_16x16x32_bf16(a4[m][ks], bLo[n][ks], acc[m][n], 0, 0, 0);
    __builtin_amdgcn_s_setprio(0);
    SBAR();

    // ---- phase 1: (m0..3, n2..3); no stage
#pragma unroll
    for (int n = 0; n < 2; ++n)
#pragma unroll
        for (int ks = 0; ks < 2; ++ks)
            bHi[n][ks] = *(const bf16x8*)&Bb[frag_off(rB + (n + 2) * 16 + l15, ks * 32 + kk)];
    SBAR(); LGKM0();
    __builtin_amdgcn_s_setprio(1);
#pragma unroll
    for (int m = 0; m < 4; ++m)
#pragma unroll
        for (int n = 0; n < 2; ++n)
#pragma unroll
            for (int ks = 0; ks < 2; ++ks)
                acc[m][n + 2] = __builtin_amdgcn_mfma_f32_16x16x32_bf16(a4[m][ks], bHi[n][ks], acc[m][n + 2], 0, 0, 0);
    __builtin_amdgcn_s_setprio(0);
    SBAR();

    // ---- phase 2: (m4..7, n2..3) reload A rows 64..127; stage (t+2):B0,B1
    //      (B-halves of cur buf last read in ph1, barrier-separated -> safe)
#pragma unroll
    for (int m = 0; m < 4; ++m)
#pragma unroll
        for (int ks = 0; ks < 2; ++ks)
            a4[m][ks] = *(const bf16x8*)&Ab[frag_off((m + 4) * 16 + l15, ks * 32 + kk)];
    if (s2) { stage_h(A, lda, B, ldb, lds, t + 2, 2, c);
              stage_h(A, lda, B, ldb, lds, t + 2, 3, c); }
    SBAR(); LGKM0();
    __builtin_amdgcn_s_setprio(1);
#pragma unroll
    for (int m = 0; m < 4; ++m)
#pragma unroll
        for (int n = 0; n < 2; ++n)
#pragma unroll
            for (int ks = 0; ks < 2; ++ks)
                acc[m + 4][n + 2] = __builtin_amdgcn_mfma_f32_16x16x32_bf16(a4[m][ks], bHi[n][ks], acc[m + 4][n + 2], 0, 0, 0);
    __builtin_amdgcn_s_setprio(0);
    SBAR();

    // ---- phase 3: (m4..7, n0..1) register-only; stage (t+2):A0
    //      (A-halves of cur buf last read in ph2, barrier-separated -> safe)
    if (s2) stage_h(A, lda, B, ldb, lds, t + 2, 0, c);
    __builtin_amdgcn_s_setprio(1);
#pragma unroll
    for (int m = 0; m < 4; ++m)
#pragma unroll
        for (int n = 0; n < 2; ++n)
#pragma unroll
            for (int ks = 0; ks < 2; ++ks)
                acc[m + 4][n] = __builtin_amdgcn_mfma_f32_16x16x32_bf16(a4[m][ks], bLo[n][ks], acc[m + 4][n], 0, 0, 0);
    __builtin_amdgcn_s_setprio(0);
    // boundary: ensure tile t+1 landed; keep (t+2):B0,B1,A0 (6 loads) in flight
    if (s1) { if (s2) VM6(); else VM0(); }
    SBAR();
}

__device__ __forceinline__ void gemm256(
    const ushort_t* __restrict__ A, int lda,
    const ushort_t* __restrict__ B, int ldb,
    ushort_t* lds, int NT, f32x4 acc[8][4])
{
    const int c = threadIdx.x;
    const int lane = c & 63, wid = c >> 6;
    const int wm = wid >> 2, wn = wid & 3;
    // prologue: tile0 complete + tile1's B0,B1,A0 (A1 comes at tile0 ph0)
    stage_h(A, lda, B, ldb, lds, 0, 0, c);
    stage_h(A, lda, B, ldb, lds, 0, 1, c);
    stage_h(A, lda, B, ldb, lds, 0, 2, c);
    stage_h(A, lda, B, ldb, lds, 0, 3, c);
    if (NT > 1) {
        stage_h(A, lda, B, ldb, lds, 1, 2, c);
        stage_h(A, lda, B, ldb, lds, 1, 3, c);
        stage_h(A, lda, B, ldb, lds, 1, 0, c);
        VM6();                    // tile0 landed; tile1's 3 halves in flight
    } else {
        VM0();
    }
    SBAR();
    for (int t = 0; t < NT; ++t)
        ktile256(A, lda, B, ldb, lds, t, NT, c, lane, wm, wn, acc);
}

// ---------------------------------------------------------------------------
// Kernel 0a/0b: fp32 -> bf16 converts
// ---------------------------------------------------------------------------
__global__ __launch_bounds__(256) void conv_x(
    const float* __restrict__ X, ushort_t* __restrict__ Xb)
{
    size_t t = (size_t)blockIdx.x * 256 + threadIdx.x;
    size_t base = t * 8;
    float4 f0 = *(const float4*)&X[base];
    float4 f1 = *(const float4*)&X[base + 4];
    U16 o;
    o.u[0] = f2bf(f0.x); o.u[1] = f2bf(f0.y); o.u[2] = f2bf(f0.z); o.u[3] = f2bf(f0.w);
    o.u[4] = f2bf(f1.x); o.u[5] = f2bf(f1.y); o.u[6] = f2bf(f1.z); o.u[7] = f2bf(f1.w);
    *(int4*)&Xb[base] = o.v;
}

__global__ __launch_bounds__(256) void conv_w(
    const float* __restrict__ Wq, const float* __restrict__ Wk,
    const float* __restrict__ Wv, ushort_t* __restrict__ Wb)
{
    size_t t = (size_t)blockIdx.x * 256 + threadIdx.x;
    size_t base = t * 8;
    int z = (int)(base >> 20);
    size_t off = base & ((1u << 20) - 1);
    const float* W = (z == 0) ? Wq : ((z == 1) ? Wk : Wv);
    float4 f0 = *(const float4*)&W[off];
    float4 f1 = *(const float4*)&W[off + 4];
    U16 o;
    o.u[0] = f2bf(f0.x); o.u[1] = f2bf(f0.y); o.u[2] = f2bf(f0.z); o.u[3] = f2bf(f0.w);
    o.u[4] = f2bf(f1.x); o.u[5] = f2bf(f1.y); o.u[6] = f2bf(f1.z); o.u[7] = f2bf(f1.w);
    *(int4*)&Wb[base] = o.v;
}

// ---------------------------------------------------------------------------
// Kernel 1: QKV projection, 256^2 counted-vmcnt. grid (12, 32).
// ---------------------------------------------------------------------------
__global__ __launch_bounds__(512, 2) void qkv_gemm256(
    const ushort_t* __restrict__ Xb, const ushort_t* __restrict__ Wb,
    ushort_t* __restrict__ QKV)
{
    __shared__ __align__(16) ushort_t lds[65536];  // 128 KB
    const int bm = blockIdx.y, bn = blockIdx.x;
    f32x4 acc[8][4] = {};
    gemm256(Xb + (size_t)bm * 256 * 1024, 1024,
            Wb + (size_t)bn * 256 * 1024, 1024, lds, 16, acc);
    const int z = bn >> 2;
    ushort_t* Dst = QKV + (size_t)z * 8192 * 1024
                  + (size_t)bm * 256 * 1024 + (bn & 3) * 256;
    const int tid = threadIdx.x, lane = tid & 63, wid = tid >> 6;
    const int wm = wid >> 2, wn = wid & 3;
#pragma unroll
    for (int m = 0; m < 8; ++m)
#pragma unroll
        for (int n = 0; n < 4; ++n)
#pragma unroll
            for (int j = 0; j < 4; ++j) {
                int row = wm * 128 + m * 16 + (lane >> 4) * 4 + j;
                int col = wn * 64 + n * 16 + (lane & 15);
                Dst[(size_t)row * 1024 + col] = f2bf(acc[m][n][j]);
            }
}

// ---------------------------------------------------------------------------
// Kernel 2: scores = (Q @ K^T)/32, 256^2, causal block-skip. grid (8, 8, 4).
// ---------------------------------------------------------------------------
__global__ __launch_bounds__(512, 2) void scores_gemm256(
    const ushort_t* __restrict__ Q, const ushort_t* __restrict__ Kb,
    ushort_t* __restrict__ P)
{
    const int b = blockIdx.z, bm = blockIdx.y, bn = blockIdx.x;
    if (bn > bm) return;
    __shared__ __align__(16) ushort_t lds[65536];
    f32x4 acc[8][4] = {};
    gemm256(Q  + (size_t)b * 2048 * 1024 + (size_t)bm * 256 * 1024, 1024,
            Kb + (size_t)b * 2048 * 1024 + (size_t)bn * 256 * 1024, 1024,
            lds, 16, acc);
    ushort_t* Pb = P + (size_t)b * 2048 * 2048 + (size_t)bm * 256 * 2048 + bn * 256;
    const int tid = threadIdx.x, lane = tid & 63, wid = tid >> 6;
    const int wm = wid >> 2, wn = wid & 3;
#pragma unroll
    for (int m = 0; m < 8; ++m)
#pragma unroll
        for (int n = 0; n < 4; ++n)
#pragma unroll
            for (int j = 0; j < 4; ++j) {
                int row = wm * 128 + m * 16 + (lane >> 4) * 4 + j;
                int col = wn * 64 + n * 16 + (lane & 15);
                Pb[(size_t)row * 2048 + col] = f2bf(acc[m][n][j] * 0.03125f);
            }
}

// ---------------------------------------------------------------------------
// Kernel 3: row softmax in place on P (bf16), causal by index.
// Only touches k < kmax = ((q>>7)+1)*128 — pv never reads beyond.
// ---------------------------------------------------------------------------
__global__ __launch_bounds__(256) void softmax_rows(ushort_t* __restrict__ P)
{
    const int q = blockIdx.x, b = blockIdx.y;
    ushort_t* row = P + ((size_t)b * 2048 + q) * 2048;
    const int tid = threadIdx.x;
    const int kmax = ((q >> 7) + 1) * 128;
    const bool active = tid * 8 < kmax;
    float v[8];
    float m = -3.0e38f;
    if (active) {
        U16 in;
        in.v = *(const int4*)&row[tid * 8];
#pragma unroll
        for (int j = 0; j < 8; ++j) {
            int k = tid * 8 + j;
            float s = bf2f(in.u[j]);
            v[j] = (k <= q) ? s : -3.0e38f;
            m = fmaxf(m, v[j]);
        }
    } else {
#pragma unroll
        for (int j = 0; j < 8; ++j) v[j] = -3.0e38f;
    }
#pragma unroll
    for (int off = 32; off >= 1; off >>= 1) m = fmaxf(m, __shfl_xor(m, off));
    __shared__ float red[4];
    if ((tid & 63) == 0) red[tid >> 6] = m;
    __syncthreads();
    m = fmaxf(fmaxf(red[0], red[1]), fmaxf(red[2], red[3]));
    float e[8], s = 0.f;
#pragma unroll
    for (int j = 0; j < 8; ++j) {
        e[j] = (v[j] > -1.0e38f) ? __expf(v[j] - m) : 0.f;
        s += e[j];
    }
#pragma unroll
    for (int off = 32; off >= 1; off >>= 1) s += __shfl_xor(s, off);
    __syncthreads();
    if ((tid & 63) == 0) red[tid >> 6] = s;
    __syncthreads();
    s = red[0] + red[1] + red[2] + red[3];
    float inv = 1.f / s;
    if (active) {
        U16 outv;
#pragma unroll
        for (int j = 0; j < 8; ++j) outv.u[j] = f2bf(e[j] * inv);
        *(int4*)&row[tid * 8] = outv.v;
    }
}

// ---------------------------------------------------------------------------
// Kernel 4: V transpose per batch. grid (32, 16, 4).
// ---------------------------------------------------------------------------
__global__ __launch_bounds__(256) void transpose_v(
    const ushort_t* __restrict__ V, ushort_t* __restrict__ Vt)
{
    __shared__ ushort_t ts[64][72];
    const int b = blockIdx.z;
    const ushort_t* Vb = V + (size_t)b * 2048 * 1024;
    ushort_t* Vtb = Vt + (size_t)b * 1024 * 2048;
    const int k0 = blockIdx.x * 64, d0 = blockIdx.y * 64;
    const int tid = threadIdx.x;
#pragma unroll
    for (int i = 0; i < 2; ++i) {
        int c = tid + 256 * i;
        int row = c >> 3, col8 = c & 7;
        U16 vv;
        vv.v = *(const int4*)&Vb[(size_t)(k0 + row) * 1024 + d0 + col8 * 8];
#pragma unroll
        for (int j = 0; j < 8; ++j) ts[row][col8 * 8 + j] = vv.u[j];
    }
    __syncthreads();
#pragma unroll
    for (int i = 0; i < 2; ++i) {
        int c = tid + 256 * i;
        int drow = c >> 3, kcol8 = c & 7;
        U16 vv;
#pragma unroll
        for (int j = 0; j < 8; ++j) vv.u[j] = ts[kcol8 * 8 + j][drow];
        *(int4*)&Vtb[(size_t)(d0 + drow) * 2048 + k0 + kcol8 * 8] = vv.v;
    }
}

// ---------------------------------------------------------------------------
// Kernel 5: O = P @ V via Vt, m97-128^2, K capped at diagonal, heavy-first.
// grid (8, 16, 4); bm = 15 - blockIdx.y so K=2048 blocks dispatch first.
// ---------------------------------------------------------------------------
__device__ __forceinline__ void stage_tile(
    const ushort_t* __restrict__ A, int lda, int k0, ushort_t* As, int tid)
{
#pragma unroll
    for (int i = 0; i < 2; ++i) {
        int c = tid + 256 * i;
        gll16(&A[(size_t)(c >> 2) * lda + k0 + (c & 3) * 8], &As[c * 8]);
    }
}

__global__ __launch_bounds__(256) void pv_gemm(
    const ushort_t* __restrict__ P, const ushort_t* __restrict__ Vt,
    float* __restrict__ O)
{
    const int b = blockIdx.z;
    const int bm = 15 - blockIdx.y;  // heavy (K=2048) blocks first
    const int bn = blockIdx.x;
    const int tid = threadIdx.x;
    __shared__ __align__(16) ushort_t As[128 * 32];
    __shared__ __align__(16) ushort_t Bs[128 * 32];
    const ushort_t* A = P + (size_t)b * 2048 * 2048 + (size_t)bm * 128 * 2048;
    const ushort_t* Bm = Vt + (size_t)b * 1024 * 2048 + (size_t)bn * 128 * 2048;
    const int lane = tid & 63, wid = tid >> 6;
    const int wr = wid >> 1, wc = wid & 1;
    f32x4 acc[4][4] = {};
    const int kEnd = (bm + 1) * 128;
    for (int k0 = 0; k0 < kEnd; k0 += 32) {
        stage_tile(A, 2048, k0, As, tid);
        stage_tile(Bm, 2048, k0, Bs, tid);
        __syncthreads();
        const int koff = (lane >> 4) * 8;
        bf16x8 a[4], bb[4];
#pragma unroll
        for (int m = 0; m < 4; ++m)
            a[m] = *(const bf16x8*)&As[(wr * 64 + m * 16 + (lane & 15)) * 32 + koff];
#pragma unroll
        for (int n = 0; n < 4; ++n)
            bb[n] = *(const bf16x8*)&Bs[(wc * 64 + n * 16 + (lane & 15)) * 32 + koff];
#pragma unroll
        for (int m = 0; m < 4; ++m)
#pragma unroll
            for (int n = 0; n < 4; ++n)
                acc[m][n] = __builtin_amdgcn_mfma_f32_16x16x32_bf16(a[m], bb[n], acc[m][n], 0, 0, 0);
        __syncthreads();
    }
    float* Ob = O + (size_t)b * 2048 * 1024 + (size_t)bm * 128 * 1024 + bn * 128;
#pragma unroll
    for (int m = 0; m < 4; ++m)
#pragma unroll
        for (int n = 0; n < 4; ++n)
#pragma unroll
            for (int j = 0; j < 4; ++j) {
                int row = wr * 64 + m * 16 + (lane >> 4) * 4 + j;
                int col = wc * 64 + n * 16 + (lane & 15);
                Ob[(size_t)row * 1024 + col] = acc[m][n][j];
            }
}

// ---------------------------------------------------------------------------
// Workspace (bf16 elems), 48M total:
//   phase 1: Xb [8192][1024] @0 (8M), Wb [3072][1024] @8M (3M) -- dead after qkv
//   phase 2: P [4][2048][2048] @0 (16M, aliases Xb/Wb)
//   q @16M, k @24M, v @32M, vt @40M
// ---------------------------------------------------------------------------
extern "C" void kernel_launch(void* const* d_in, const int* in_sizes, int n_in,
                              void* d_out, int out_size, void* d_ws, size_t ws_size,
                              hipStream_t stream) {
    const float* x  = (const float*)d_in[0];
    const float* Wq = (const float*)d_in[1];
    const float* Wk = (const float*)d_in[2];
    const float* Wv = (const float*)d_in[3];
    float* out = (float*)d_out;
    ushort_t* ws = (ushort_t*)d_ws;
    ushort_t* Xb = ws;
    ushort_t* Wb = ws + (size_t)8192 * 1024;
    ushort_t* P  = ws;
    ushort_t* qb = ws + (size_t)16 * 1024 * 1024;
    ushort_t* kb = qb + (size_t)8192 * 1024;
    ushort_t* vb = kb + (size_t)8192 * 1024;
    ushort_t* vt = vb + (size_t)8192 * 1024;

    conv_x<<<dim3(4096), 256, 0, stream>>>(x, Xb);
    conv_w<<<dim3(1536), 256, 0, stream>>>(Wq, Wk, Wv, Wb);
    qkv_gemm256<<<dim3(12, 32), 512, 0, stream>>>(Xb, Wb, qb);
    scores_gemm256<<<dim3(8, 8, 4), 512, 0, stream>>>(qb, kb, P);
    softmax_rows<<<dim3(2048, 4), 256, 0, stream>>>(P);
    transpose_v<<<dim3(32, 16, 4), 256, 0, stream>>>(vb, vt);
    pv_gemm<<<dim3(8, 16, 4), 256, 0, stream>>>(P, vt, out);
}

// Round 6
// 180.080 us; speedup vs baseline: 1.4456x; 1.0449x over previous
//
#include <hip/hip_runtime.h>
#include <hip/hip_bf16.h>

typedef unsigned int uint32;
typedef unsigned short ushort_t;

typedef __bf16 bf16x8 __attribute__((ext_vector_type(8)));
typedef float f32x4 __attribute__((ext_vector_type(4)));

__device__ __forceinline__ ushort_t f2bf(float f) {
    uint32 u = __float_as_uint(f);
    u += 0x7fffu + ((u >> 16) & 1u);
    return (ushort_t)(u >> 16);
}
__device__ __forceinline__ float bf2f(ushort_t h) {
    return __uint_as_float(((uint32)h) << 16);
}

union U16 { int4 v; ushort_t u[8]; };

// async global->LDS, 16B per lane (dest = wave-uniform base + lane*16)
__device__ __forceinline__ void gll16(const ushort_t* g, ushort_t* l) {
    __builtin_amdgcn_global_load_lds(
        (const __attribute__((address_space(1))) unsigned int*)g,
        (__attribute__((address_space(3))) unsigned int*)l, 16, 0, 0);
}

#define SBAR() __builtin_amdgcn_s_barrier()
#define VM0()  asm volatile("s_waitcnt vmcnt(0)" ::: "memory")
#define VM1()  asm volatile("s_waitcnt vmcnt(1)" ::: "memory")

// ===========================================================================
// 256x256 GEMM, BK=32, 1024 threads = 16 waves (4M x 4N), wave tile 64x64.
// 16 waves/CU = 4/SIMD: TLP does the latency hiding (m114) -> only ONE
// barrier per K-tile.
// LDS 96KB = 3-buffer ring x {A,B} x [256][32] bf16 (16KB pieces).
//
// 3-ring staging (race-free without intra-tile barriers):
//   tile t stages (t+1):A -> buf (t+1)%3  (readers = tile t-2, done long ago)
//              and (t+2):B -> buf (t+2)%3 (readers = tile t-1, done at last
//                                          barrier, before these issues)
//   boundary: vmcnt(1) -> (t+1)'s A and B landed (per-wave), 1 load in
//   flight; SBAR makes it collective. Never drains to 0 mid-loop (T4).
//
// Swizzle (BK=32): row r's 4 16B-slots permuted by slot ^= (r>>1)&3.
//   16 lanes reading one k-slot across rows r..r+15 -> each bank-quad hit
//   exactly 2x = free. Source pre-permuted, LDS linear (rule #21).
// ===========================================================================
__device__ __forceinline__ int frag3(int r, int kk) {  // kk in {0,8,16,24}
    return r * 32 + ((((kk >> 3) ^ ((r >> 1) & 3))) << 3);
}

template<int NT>
__device__ __forceinline__ void gemm256_bk32(
    const ushort_t* __restrict__ A, int lda,
    const ushort_t* __restrict__ B, int ldb,
    ushort_t* lds, f32x4 acc[4][4])
{
    const int tid = threadIdx.x;
    const int lane = tid & 63, wid = tid >> 6;
    const int wm = wid >> 2, wn = wid & 3;
    const int l15 = lane & 15, kk = (lane >> 4) * 8;
    // staging: op panel is 256x32 bf16 = 16KB = 1024 chunks; 1 gll/thread
    const int srow = tid >> 2;
    const int sc4 = (tid & 3) ^ ((tid >> 3) & 3);   // inverse swizzle on src

    #define STAGE3(G, ldg, X, op)                                            \
        gll16(&(G)[(size_t)srow * (ldg) + (X) * 32 + sc4 * 8],               \
              &lds[(((X) % 3) * 2 + (op)) * 8192 + tid * 8])

    // prologue: t0:A, t0:B, t1:B in flight; wait t0 (leave t1:B)
    STAGE3(A, lda, 0, 0);
    STAGE3(B, ldb, 0, 1);
    if (NT > 1) { STAGE3(B, ldb, 1, 1); VM1(); } else { VM0(); }
    SBAR();

    for (int t = 0; t < NT; ++t) {
        const ushort_t* Ab = lds + (t % 3) * 16384;
        const ushort_t* Bb = Ab + 8192;
        if (t + 1 < NT) STAGE3(A, lda, t + 1, 0);
        if (t + 2 < NT) STAGE3(B, ldb, t + 2, 1);
        bf16x8 af[4], bfr[4];
#pragma unroll
        for (int m = 0; m < 4; ++m)
            af[m] = *(const bf16x8*)&Ab[frag3(wm * 64 + m * 16 + l15, kk)];
#pragma unroll
        for (int n = 0; n < 4; ++n)
            bfr[n] = *(const bf16x8*)&Bb[frag3(wn * 64 + n * 16 + l15, kk)];
#pragma unroll
        for (int m = 0; m < 4; ++m)
#pragma unroll
            for (int n = 0; n < 4; ++n)
                acc[m][n] = __builtin_amdgcn_mfma_f32_16x16x32_bf16(
                    af[m], bfr[n], acc[m][n], 0, 0, 0);
        if (t + 1 < NT) {
            if (t + 2 < NT) VM1(); else VM0();
            SBAR();
        }
    }
    #undef STAGE3
}

// ---------------------------------------------------------------------------
// Kernel 0: fused fp32 -> bf16 converts (X then W). grid 4096+1536.
// ---------------------------------------------------------------------------
__global__ __launch_bounds__(256) void conv_all(
    const float* __restrict__ X,
    const float* __restrict__ Wq, const float* __restrict__ Wk,
    const float* __restrict__ Wv,
    ushort_t* __restrict__ Xb, ushort_t* __restrict__ Wb)
{
    int gb = blockIdx.x;
    const float* src;
    ushort_t* dst;
    size_t base;
    if (gb < 4096) {
        base = ((size_t)gb * 256 + threadIdx.x) * 8;
        src = X + base; dst = Xb + base;
    } else {
        base = ((size_t)(gb - 4096) * 256 + threadIdx.x) * 8;
        int z = (int)(base >> 20);
        size_t off = base & ((1u << 20) - 1);
        src = ((z == 0) ? Wq : ((z == 1) ? Wk : Wv)) + off;
        dst = Wb + base;
    }
    float4 f0 = *(const float4*)src;
    float4 f1 = *(const float4*)(src + 4);
    U16 o;
    o.u[0] = f2bf(f0.x); o.u[1] = f2bf(f0.y); o.u[2] = f2bf(f0.z); o.u[3] = f2bf(f0.w);
    o.u[4] = f2bf(f1.x); o.u[5] = f2bf(f1.y); o.u[6] = f2bf(f1.z); o.u[7] = f2bf(f1.w);
    *(int4*)dst = o.v;
}

// ---------------------------------------------------------------------------
// Kernel 1: QKV projection, 256^2 BK=32 16-wave. grid (12, 32), 1024 thr.
// ---------------------------------------------------------------------------
__global__ __launch_bounds__(1024) void qkv_gemm256(
    const ushort_t* __restrict__ Xb, const ushort_t* __restrict__ Wb,
    ushort_t* __restrict__ QKV)
{
    __shared__ __align__(16) ushort_t lds[49152];  // 96 KB
    const int bm = blockIdx.y, bn = blockIdx.x;
    f32x4 acc[4][4] = {};
    gemm256_bk32<32>(Xb + (size_t)bm * 256 * 1024, 1024,
                     Wb + (size_t)bn * 256 * 1024, 1024, lds, acc);
    const int z = bn >> 2;
    ushort_t* Dst = QKV + (size_t)z * 8192 * 1024
                  + (size_t)bm * 256 * 1024 + (bn & 3) * 256;
    const int tid = threadIdx.x, lane = tid & 63, wid = tid >> 6;
    const int wm = wid >> 2, wn = wid & 3;
#pragma unroll
    for (int m = 0; m < 4; ++m)
#pragma unroll
        for (int n = 0; n < 4; ++n)
#pragma unroll
            for (int j = 0; j < 4; ++j) {
                int row = wm * 64 + m * 16 + (lane >> 4) * 4 + j;
                int col = wn * 64 + n * 16 + (lane & 15);
                Dst[(size_t)row * 1024 + col] = f2bf(acc[m][n][j]);
            }
}

// ---------------------------------------------------------------------------
// Kernel 2: scores = (Q @ K^T)/32, 256^2 BK=32 16-wave, causal block-skip;
// masked blocks (bn > bm) do the V-transpose instead (hidden under scores).
// grid (8, 8, 4), 1024 thr.
// ---------------------------------------------------------------------------
__global__ __launch_bounds__(1024) void scores_gemm256(
    const ushort_t* __restrict__ Q, const ushort_t* __restrict__ Kb,
    ushort_t* __restrict__ P,
    const ushort_t* __restrict__ V, ushort_t* __restrict__ Vt)
{
    __shared__ __align__(16) ushort_t lds[49152];
    const int b = blockIdx.z, bm = blockIdx.y, bn = blockIdx.x;
    const int tid = threadIdx.x;
    if (bn > bm) {
        // ---- V-transpose duty: 512 64x64 tiles/batch over 28 masked blocks
        ushort_t (*ts)[72] = (ushort_t(*)[72])lds;
        const ushort_t* Vb = V + (size_t)b * 2048 * 1024;
        ushort_t* Vtb = Vt + (size_t)b * 1024 * 2048;
        const int rank = bn * (bn - 1) / 2 + bm;   // [0,28)
        for (int t = rank; t < 512; t += 28) {
            int k0 = (t >> 4) * 64, d0 = (t & 15) * 64;
            __syncthreads();
            if (tid < 512) {
                int row = tid >> 3, col8 = tid & 7;
                U16 vv;
                vv.v = *(const int4*)&Vb[(size_t)(k0 + row) * 1024 + d0 + col8 * 8];
#pragma unroll
                for (int j = 0; j < 8; ++j) ts[row][col8 * 8 + j] = vv.u[j];
            }
            __syncthreads();
            if (tid < 512) {
                int drow = tid >> 3, kcol8 = tid & 7;
                U16 vv;
#pragma unroll
                for (int j = 0; j < 8; ++j) vv.u[j] = ts[kcol8 * 8 + j][drow];
                *(int4*)&Vtb[(size_t)(d0 + drow) * 2048 + k0 + kcol8 * 8] = vv.v;
            }
        }
        return;
    }
    f32x4 acc[4][4] = {};
    gemm256_bk32<32>(Q  + (size_t)b * 2048 * 1024 + (size_t)bm * 256 * 1024, 1024,
                     Kb + (size_t)b * 2048 * 1024 + (size_t)bn * 256 * 1024, 1024,
                     lds, acc);
    ushort_t* Pb = P + (size_t)b * 2048 * 2048 + (size_t)bm * 256 * 2048 + bn * 256;
    const int lane = tid & 63, wid = tid >> 6;
    const int wm = wid >> 2, wn = wid & 3;
#pragma unroll
    for (int m = 0; m < 4; ++m)
#pragma unroll
        for (int n = 0; n < 4; ++n)
#pragma unroll
            for (int j = 0; j < 4; ++j) {
                int row = wm * 64 + m * 16 + (lane >> 4) * 4 + j;
                int col = wn * 64 + n * 16 + (lane & 15);
                Pb[(size_t)row * 2048 + col] = f2bf(acc[m][n][j] * 0.03125f);
            }
}

// ---------------------------------------------------------------------------
// Kernel 3: row softmax in place on P (bf16), causal by index.
// Only touches k < kmax = ((q>>7)+1)*128 — pv never reads beyond.
// ---------------------------------------------------------------------------
__global__ __launch_bounds__(256) void softmax_rows(ushort_t* __restrict__ P)
{
    const int q = blockIdx.x, b = blockIdx.y;
    ushort_t* row = P + ((size_t)b * 2048 + q) * 2048;
    const int tid = threadIdx.x;
    const int kmax = ((q >> 7) + 1) * 128;
    const bool active = tid * 8 < kmax;
    float v[8];
    float m = -3.0e38f;
    if (active) {
        U16 in;
        in.v = *(const int4*)&row[tid * 8];
#pragma unroll
        for (int j = 0; j < 8; ++j) {
            int k = tid * 8 + j;
            float s = bf2f(in.u[j]);
            v[j] = (k <= q) ? s : -3.0e38f;
            m = fmaxf(m, v[j]);
        }
    } else {
#pragma unroll
        for (int j = 0; j < 8; ++j) v[j] = -3.0e38f;
    }
#pragma unroll
    for (int off = 32; off >= 1; off >>= 1) m = fmaxf(m, __shfl_xor(m, off));
    __shared__ float red[4];
    if ((tid & 63) == 0) red[tid >> 6] = m;
    __syncthreads();
    m = fmaxf(fmaxf(red[0], red[1]), fmaxf(red[2], red[3]));
    float e[8], s = 0.f;
#pragma unroll
    for (int j = 0; j < 8; ++j) {
        e[j] = (v[j] > -1.0e38f) ? __expf(v[j] - m) : 0.f;
        s += e[j];
    }
#pragma unroll
    for (int off = 32; off >= 1; off >>= 1) s += __shfl_xor(s, off);
    __syncthreads();
    if ((tid & 63) == 0) red[tid >> 6] = s;
    __syncthreads();
    s = red[0] + red[1] + red[2] + red[3];
    float inv = 1.f / s;
    if (active) {
        U16 outv;
#pragma unroll
        for (int j = 0; j < 8; ++j) outv.u[j] = f2bf(e[j] * inv);
        *(int4*)&row[tid * 8] = outv.v;
    }
}

// ---------------------------------------------------------------------------
// Kernel 5: O = P @ V via Vt, m97-128^2, K capped at diagonal, heavy-first.
// grid (8, 16, 4); bm = 15 - blockIdx.y so K=2048 blocks dispatch first.
// ---------------------------------------------------------------------------
__device__ __forceinline__ void stage_tile(
    const ushort_t* __restrict__ A, int lda, int k0, ushort_t* As, int tid)
{
#pragma unroll
    for (int i = 0; i < 2; ++i) {
        int c = tid + 256 * i;
        gll16(&A[(size_t)(c >> 2) * lda + k0 + (c & 3) * 8], &As[c * 8]);
    }
}

__global__ __launch_bounds__(256) void pv_gemm(
    const ushort_t* __restrict__ P, const ushort_t* __restrict__ Vt,
    float* __restrict__ O)
{
    const int b = blockIdx.z;
    const int bm = 15 - blockIdx.y;  // heavy (K=2048) blocks first
    const int bn = blockIdx.x;
    const int tid = threadIdx.x;
    __shared__ __align__(16) ushort_t As[128 * 32];
    __shared__ __align__(16) ushort_t Bs[128 * 32];
    const ushort_t* A = P + (size_t)b * 2048 * 2048 + (size_t)bm * 128 * 2048;
    const ushort_t* Bm = Vt + (size_t)b * 1024 * 2048 + (size_t)bn * 128 * 2048;
    const int lane = tid & 63, wid = tid >> 6;
    const int wr = wid >> 1, wc = wid & 1;
    f32x4 acc[4][4] = {};
    const int kEnd = (bm + 1) * 128;
    for (int k0 = 0; k0 < kEnd; k0 += 32) {
        stage_tile(A, 2048, k0, As, tid);
        stage_tile(Bm, 2048, k0, Bs, tid);
        __syncthreads();
        const int koff = (lane >> 4) * 8;
        bf16x8 a[4], bb[4];
#pragma unroll
        for (int m = 0; m < 4; ++m)
            a[m] = *(const bf16x8*)&As[(wr * 64 + m * 16 + (lane & 15)) * 32 + koff];
#pragma unroll
        for (int n = 0; n < 4; ++n)
            bb[n] = *(const bf16x8*)&Bs[(wc * 64 + n * 16 + (lane & 15)) * 32 + koff];
#pragma unroll
        for (int m = 0; m < 4; ++m)
#pragma unroll
            for (int n = 0; n < 4; ++n)
                acc[m][n] = __builtin_amdgcn_mfma_f32_16x16x32_bf16(a[m], bb[n], acc[m][n], 0, 0, 0);
        __syncthreads();
    }
    float* Ob = O + (size_t)b * 2048 * 1024 + (size_t)bm * 128 * 1024 + bn * 128;
#pragma unroll
    for (int m = 0; m < 4; ++m)
#pragma unroll
        for (int n = 0; n < 4; ++n)
#pragma unroll
            for (int j = 0; j < 4; ++j) {
                int row = wr * 64 + m * 16 + (lane >> 4) * 4 + j;
                int col = wc * 64 + n * 16 + (lane & 15);
                Ob[(size_t)row * 1024 + col] = acc[m][n][j];
            }
}

// ---------------------------------------------------------------------------
// Workspace (bf16 elems), 48M total:
//   phase 1: Xb [8192][1024] @0 (8M), Wb [3072][1024] @8M (3M) -- dead after qkv
//   phase 2: P [4][2048][2048] @0 (16M, aliases Xb/Wb)
//   q @16M, k @24M, v @32M, vt @40M
// ---------------------------------------------------------------------------
extern "C" void kernel_launch(void* const* d_in, const int* in_sizes, int n_in,
                              void* d_out, int out_size, void* d_ws, size_t ws_size,
                              hipStream_t stream) {
    const float* x  = (const float*)d_in[0];
    const float* Wq = (const float*)d_in[1];
    const float* Wk = (const float*)d_in[2];
    const float* Wv = (const float*)d_in[3];
    float* out = (float*)d_out;
    ushort_t* ws = (ushort_t*)d_ws;
    ushort_t* Xb = ws;
    ushort_t* Wb = ws + (size_t)8192 * 1024;
    ushort_t* P  = ws;
    ushort_t* qb = ws + (size_t)16 * 1024 * 1024;
    ushort_t* kb = qb + (size_t)8192 * 1024;
    ushort_t* vb = kb + (size_t)8192 * 1024;
    ushort_t* vt = vb + (size_t)8192 * 1024;

    conv_all<<<dim3(4096 + 1536), 256, 0, stream>>>(x, Wq, Wk, Wv, Xb, Wb);
    qkv_gemm256<<<dim3(12, 32), 1024, 0, stream>>>(Xb, Wb, qb);
    scores_gemm256<<<dim3(8, 8, 4), 1024, 0, stream>>>(qb, kb, P, vb, vt);
    softmax_rows<<<dim3(2048, 4), 256, 0, stream>>>(P);
    pv_gemm<<<dim3(8, 16, 4), 256, 0, stream>>>(P, vt, out);
}

// Round 7
// 177.402 us; speedup vs baseline: 1.4675x; 1.0151x over previous
//
#include <hip/hip_runtime.h>
#include <hip/hip_bf16.h>

typedef unsigned int uint32;
typedef unsigned short ushort_t;

typedef __bf16 bf16x8 __attribute__((ext_vector_type(8)));
typedef float f32x4 __attribute__((ext_vector_type(4)));

__device__ __forceinline__ ushort_t f2bf(float f) {
    uint32 u = __float_as_uint(f);
    u += 0x7fffu + ((u >> 16) & 1u);
    return (ushort_t)(u >> 16);
}
__device__ __forceinline__ float bf2f(ushort_t h) {
    return __uint_as_float(((uint32)h) << 16);
}

union U16 { int4 v; ushort_t u[8]; };

// async global->LDS, 16B per lane (dest = wave-uniform base + lane*16)
__device__ __forceinline__ void gll16(const ushort_t* g, ushort_t* l) {
    __builtin_amdgcn_global_load_lds(
        (const __attribute__((address_space(1))) unsigned int*)g,
        (__attribute__((address_space(3))) unsigned int*)l, 16, 0, 0);
}

#define SBAR() __builtin_amdgcn_s_barrier()
#define VM0()  asm volatile("s_waitcnt vmcnt(0)" ::: "memory")
#define VM1()  asm volatile("s_waitcnt vmcnt(1)" ::: "memory")

// ===========================================================================
// 256x256 GEMM, BK=32, 1024 threads = 16 waves (4M x 4N), wave tile 64x64.
// 3-buffer LDS ring (96KB), one barrier per K-tile, counted vmcnt (never 0
// mid-loop). Swizzle: row r slot ^= (r>>1)&3, source-pre-permuted (rule #21).
// Measured (R6): Tblock ~= 32.5us, bank conflicts 0, VGPR 64.
// ===========================================================================
__device__ __forceinline__ int frag3(int r, int kk) {  // kk in {0,8,16,24}
    return r * 32 + ((((kk >> 3) ^ ((r >> 1) & 3))) << 3);
}

template<int NT>
__device__ __forceinline__ void gemm256_bk32(
    const ushort_t* __restrict__ A, int lda,
    const ushort_t* __restrict__ B, int ldb,
    ushort_t* lds, f32x4 acc[4][4])
{
    const int tid = threadIdx.x;
    const int lane = tid & 63, wid = tid >> 6;
    const int wm = wid >> 2, wn = wid & 3;
    const int l15 = lane & 15, kk = (lane >> 4) * 8;
    const int srow = tid >> 2;
    const int sc4 = (tid & 3) ^ ((tid >> 3) & 3);   // inverse swizzle on src

    #define STAGE3(G, ldg, X, op)                                            \
        gll16(&(G)[(size_t)srow * (ldg) + (X) * 32 + sc4 * 8],               \
              &lds[(((X) % 3) * 2 + (op)) * 8192 + tid * 8])

    STAGE3(A, lda, 0, 0);
    STAGE3(B, ldb, 0, 1);
    if (NT > 1) { STAGE3(B, ldb, 1, 1); VM1(); } else { VM0(); }
    SBAR();

    for (int t = 0; t < NT; ++t) {
        const ushort_t* Ab = lds + (t % 3) * 16384;
        const ushort_t* Bb = Ab + 8192;
        if (t + 1 < NT) STAGE3(A, lda, t + 1, 0);
        if (t + 2 < NT) STAGE3(B, ldb, t + 2, 1);
        bf16x8 af[4], bfr[4];
#pragma unroll
        for (int m = 0; m < 4; ++m)
            af[m] = *(const bf16x8*)&Ab[frag3(wm * 64 + m * 16 + l15, kk)];
#pragma unroll
        for (int n = 0; n < 4; ++n)
            bfr[n] = *(const bf16x8*)&Bb[frag3(wn * 64 + n * 16 + l15, kk)];
#pragma unroll
        for (int m = 0; m < 4; ++m)
#pragma unroll
            for (int n = 0; n < 4; ++n)
                acc[m][n] = __builtin_amdgcn_mfma_f32_16x16x32_bf16(
                    af[m], bfr[n], acc[m][n], 0, 0, 0);
        if (t + 1 < NT) {
            if (t + 2 < NT) VM1(); else VM0();
            SBAR();
        }
    }
    #undef STAGE3
}

// ---------------------------------------------------------------------------
// Kernel 0: fp32 -> bf16: X (gb<4096) and Wv -> Bmat rows 1024..2047.
// ---------------------------------------------------------------------------
__global__ __launch_bounds__(256) void conv_x(
    const float* __restrict__ X, const float* __restrict__ Wv,
    ushort_t* __restrict__ Xb, ushort_t* __restrict__ BmatV)
{
    int gb = blockIdx.x;
    const float* src;
    ushort_t* dst;
    if (gb < 4096) {
        size_t base = ((size_t)gb * 256 + threadIdx.x) * 8;
        src = X + base; dst = Xb + base;
    } else {
        size_t base = ((size_t)(gb - 4096) * 256 + threadIdx.x) * 8;
        src = Wv + base; dst = BmatV + base;
    }
    float4 f0 = *(const float4*)src;
    float4 f1 = *(const float4*)(src + 4);
    U16 o;
    o.u[0] = f2bf(f0.x); o.u[1] = f2bf(f0.y); o.u[2] = f2bf(f0.z); o.u[3] = f2bf(f0.w);
    o.u[4] = f2bf(f1.x); o.u[5] = f2bf(f1.y); o.u[6] = f2bf(f1.z); o.u[7] = f2bf(f1.w);
    *(int4*)dst = o.v;
}

// ---------------------------------------------------------------------------
// Kernel 0b: transpose+convert Wq,Wk: dstT[d][o] = src[o][d], fp32 -> bf16.
// grid (16,16,2), 64x64 tiles.
// ---------------------------------------------------------------------------
__global__ __launch_bounds__(256) void convT_w(
    const float* __restrict__ Wq, const float* __restrict__ Wk,
    ushort_t* __restrict__ WqT, ushort_t* __restrict__ WkT)
{
    __shared__ ushort_t ts[64][72];
    const float* W = blockIdx.z ? Wk : Wq;
    ushort_t* Dt = blockIdx.z ? WkT : WqT;
    const int o0 = blockIdx.x * 64, d0 = blockIdx.y * 64;
    const int tid = threadIdx.x;
    const int row = tid >> 2, q = tid & 3;
#pragma unroll
    for (int c4 = 0; c4 < 4; ++c4) {
        float4 f = *(const float4*)&W[(size_t)(o0 + row) * 1024 + d0 + q * 16 + c4 * 4];
        ts[row][q * 16 + c4 * 4 + 0] = f2bf(f.x);
        ts[row][q * 16 + c4 * 4 + 1] = f2bf(f.y);
        ts[row][q * 16 + c4 * 4 + 2] = f2bf(f.z);
        ts[row][q * 16 + c4 * 4 + 3] = f2bf(f.w);
    }
    __syncthreads();
#pragma unroll
    for (int i = 0; i < 2; ++i) {
        int c = tid + 256 * i;
        int drow = c >> 3, ocol8 = c & 7;
        U16 vv;
#pragma unroll
        for (int j = 0; j < 8; ++j) vv.u[j] = ts[ocol8 * 8 + j][drow];
        *(int4*)&Dt[(size_t)(d0 + drow) * 1024 + o0 + ocol8 * 8] = vv.v;
    }
}

// ---------------------------------------------------------------------------
// Kernel 0c: Mt GEMM (m97-128^2): Bmat[a][d] = sum_o WkT[a][o]*WqT[d][o]
//   (= M[d][a] where M = Wq^T Wk, so T1 = X @ Bmat^T gives X M).
// grid (8,8), 256 thr.
// ---------------------------------------------------------------------------
__device__ __forceinline__ void stage_tile(
    const ushort_t* __restrict__ A, int lda, int k0, ushort_t* As, int tid)
{
#pragma unroll
    for (int i = 0; i < 2; ++i) {
        int c = tid + 256 * i;
        gll16(&A[(size_t)(c >> 2) * lda + k0 + (c & 3) * 8], &As[c * 8]);
    }
}

__global__ __launch_bounds__(256) void mt_gemm(
    const ushort_t* __restrict__ WkT, const ushort_t* __restrict__ WqT,
    ushort_t* __restrict__ Bmat)
{
    const int bm = blockIdx.y, bn = blockIdx.x;
    const int tid = threadIdx.x;
    __shared__ __align__(16) ushort_t As[128 * 32];
    __shared__ __align__(16) ushort_t Bs[128 * 32];
    const ushort_t* A = WkT + (size_t)bm * 128 * 1024;
    const ushort_t* Bm = WqT + (size_t)bn * 128 * 1024;
    const int lane = tid & 63, wid = tid >> 6;
    const int wr = wid >> 1, wc = wid & 1;
    f32x4 acc[4][4] = {};
    for (int k0 = 0; k0 < 1024; k0 += 32) {
        stage_tile(A, 1024, k0, As, tid);
        stage_tile(Bm, 1024, k0, Bs, tid);
        __syncthreads();
        const int koff = (lane >> 4) * 8;
        bf16x8 a[4], bb[4];
#pragma unroll
        for (int m = 0; m < 4; ++m)
            a[m] = *(const bf16x8*)&As[(wr * 64 + m * 16 + (lane & 15)) * 32 + koff];
#pragma unroll
        for (int n = 0; n < 4; ++n)
            bb[n] = *(const bf16x8*)&Bs[(wc * 64 + n * 16 + (lane & 15)) * 32 + koff];
#pragma unroll
        for (int m = 0; m < 4; ++m)
#pragma unroll
            for (int n = 0; n < 4; ++n)
                acc[m][n] = __builtin_amdgcn_mfma_f32_16x16x32_bf16(a[m], bb[n], acc[m][n], 0, 0, 0);
        __syncthreads();
    }
    ushort_t* Dst = Bmat + (size_t)bm * 128 * 1024 + bn * 128;
#pragma unroll
    for (int m = 0; m < 4; ++m)
#pragma unroll
        for (int n = 0; n < 4; ++n)
#pragma unroll
            for (int j = 0; j < 4; ++j) {
                int row = wr * 64 + m * 16 + (lane >> 4) * 4 + j;
                int col = wc * 64 + n * 16 + (lane & 15);
                Dst[(size_t)row * 1024 + col] = f2bf(acc[m][n][j]);
            }
}

// ---------------------------------------------------------------------------
// Kernel 1: T1|V projection: [8192][1024] @ Bmat[2048][1024]^T.
// grid (8,32) = 256 blocks = exactly 1 occupancy round. 1024 thr.
// ---------------------------------------------------------------------------
__global__ __launch_bounds__(1024) void t1v_gemm256(
    const ushort_t* __restrict__ Xb, const ushort_t* __restrict__ Bmat,
    ushort_t* __restrict__ T1, ushort_t* __restrict__ V)
{
    __shared__ __align__(16) ushort_t lds[49152];  // 96 KB
    const int bm = blockIdx.y, bn = blockIdx.x;
    f32x4 acc[4][4] = {};
    gemm256_bk32<32>(Xb + (size_t)bm * 256 * 1024, 1024,
                     Bmat + (size_t)bn * 256 * 1024, 1024, lds, acc);
    ushort_t* Dst = ((bn < 4) ? T1 : V)
                  + (size_t)bm * 256 * 1024 + (bn & 3) * 256;
    const int tid = threadIdx.x, lane = tid & 63, wid = tid >> 6;
    const int wm = wid >> 2, wn = wid & 3;
#pragma unroll
    for (int m = 0; m < 4; ++m)
#pragma unroll
        for (int n = 0; n < 4; ++n)
#pragma unroll
            for (int j = 0; j < 4; ++j) {
                int row = wm * 64 + m * 16 + (lane >> 4) * 4 + j;
                int col = wn * 64 + n * 16 + (lane & 15);
                Dst[(size_t)row * 1024 + col] = f2bf(acc[m][n][j]);
            }
}

// ---------------------------------------------------------------------------
// Kernel 2: scores = (T1 @ X^T)/32, 256^2 BK=32 16-wave, causal block-skip;
// masked blocks (bn > bm) do the V-transpose instead. grid (8,8,4), 1024 thr.
// ---------------------------------------------------------------------------
__global__ __launch_bounds__(1024) void scores_gemm256(
    const ushort_t* __restrict__ T1, const ushort_t* __restrict__ Xb,
    ushort_t* __restrict__ P,
    const ushort_t* __restrict__ V, ushort_t* __restrict__ Vt)
{
    __shared__ __align__(16) ushort_t lds[49152];
    const int b = blockIdx.z, bm = blockIdx.y, bn = blockIdx.x;
    const int tid = threadIdx.x;
    if (bn > bm) {
        // ---- V-transpose duty: 512 64x64 tiles/batch over 28 masked blocks
        ushort_t (*ts)[72] = (ushort_t(*)[72])lds;
        const ushort_t* Vb = V + (size_t)b * 2048 * 1024;
        ushort_t* Vtb = Vt + (size_t)b * 1024 * 2048;
        const int rank = bn * (bn - 1) / 2 + bm;   // [0,28)
        for (int t = rank; t < 512; t += 28) {
            int k0 = (t >> 4) * 64, d0 = (t & 15) * 64;
            __syncthreads();
            if (tid < 512) {
                int row = tid >> 3, col8 = tid & 7;
                U16 vv;
                vv.v = *(const int4*)&Vb[(size_t)(k0 + row) * 1024 + d0 + col8 * 8];
#pragma unroll
                for (int j = 0; j < 8; ++j) ts[row][col8 * 8 + j] = vv.u[j];
            }
            __syncthreads();
            if (tid < 512) {
                int drow = tid >> 3, kcol8 = tid & 7;
                U16 vv;
#pragma unroll
                for (int j = 0; j < 8; ++j) vv.u[j] = ts[kcol8 * 8 + j][drow];
                *(int4*)&Vtb[(size_t)(d0 + drow) * 2048 + k0 + kcol8 * 8] = vv.v;
            }
        }
        return;
    }
    f32x4 acc[4][4] = {};
    gemm256_bk32<32>(T1 + (size_t)b * 2048 * 1024 + (size_t)bm * 256 * 1024, 1024,
                     Xb + (size_t)b * 2048 * 1024 + (size_t)bn * 256 * 1024, 1024,
                     lds, acc);
    ushort_t* Pb = P + (size_t)b * 2048 * 2048 + (size_t)bm * 256 * 2048 + bn * 256;
    const int lane = tid & 63, wid = tid >> 6;
    const int wm = wid >> 2, wn = wid & 3;
#pragma unroll
    for (int m = 0; m < 4; ++m)
#pragma unroll
        for (int n = 0; n < 4; ++n)
#pragma unroll
            for (int j = 0; j < 4; ++j) {
                int row = wm * 64 + m * 16 + (lane >> 4) * 4 + j;
                int col = wn * 64 + n * 16 + (lane & 15);
                Pb[(size_t)row * 2048 + col] = f2bf(acc[m][n][j] * 0.03125f);
            }
}

// ---------------------------------------------------------------------------
// Kernel 3: row softmax in place on P (bf16), causal by index.
// Only touches k < kmax = ((q>>7)+1)*128 — pv never reads beyond.
// ---------------------------------------------------------------------------
__global__ __launch_bounds__(256) void softmax_rows(ushort_t* __restrict__ P)
{
    const int q = blockIdx.x, b = blockIdx.y;
    ushort_t* row = P + ((size_t)b * 2048 + q) * 2048;
    const int tid = threadIdx.x;
    const int kmax = ((q >> 7) + 1) * 128;
    const bool active = tid * 8 < kmax;
    float v[8];
    float m = -3.0e38f;
    if (active) {
        U16 in;
        in.v = *(const int4*)&row[tid * 8];
#pragma unroll
        for (int j = 0; j < 8; ++j) {
            int k = tid * 8 + j;
            float s = bf2f(in.u[j]);
            v[j] = (k <= q) ? s : -3.0e38f;
            m = fmaxf(m, v[j]);
        }
    } else {
#pragma unroll
        for (int j = 0; j < 8; ++j) v[j] = -3.0e38f;
    }
#pragma unroll
    for (int off = 32; off >= 1; off >>= 1) m = fmaxf(m, __shfl_xor(m, off));
    __shared__ float red[4];
    if ((tid & 63) == 0) red[tid >> 6] = m;
    __syncthreads();
    m = fmaxf(fmaxf(red[0], red[1]), fmaxf(red[2], red[3]));
    float e[8], s = 0.f;
#pragma unroll
    for (int j = 0; j < 8; ++j) {
        e[j] = (v[j] > -1.0e38f) ? __expf(v[j] - m) : 0.f;
        s += e[j];
    }
#pragma unroll
    for (int off = 32; off >= 1; off >>= 1) s += __shfl_xor(s, off);
    __syncthreads();
    if ((tid & 63) == 0) red[tid >> 6] = s;
    __syncthreads();
    s = red[0] + red[1] + red[2] + red[3];
    float inv = 1.f / s;
    if (active) {
        U16 outv;
#pragma unroll
        for (int j = 0; j < 8; ++j) outv.u[j] = f2bf(e[j] * inv);
        *(int4*)&row[tid * 8] = outv.v;
    }
}

// ---------------------------------------------------------------------------
// Kernel 5: O = P @ V via Vt, m97-128^2, K capped at diagonal, heavy-first.
// grid (8, 16, 4); bm = 15 - blockIdx.y so K=2048 blocks dispatch first.
// ---------------------------------------------------------------------------
__global__ __launch_bounds__(256) void pv_gemm(
    const ushort_t* __restrict__ P, const ushort_t* __restrict__ Vt,
    float* __restrict__ O)
{
    const int b = blockIdx.z;
    const int bm = 15 - blockIdx.y;  // heavy (K=2048) blocks first
    const int bn = blockIdx.x;
    const int tid = threadIdx.x;
    __shared__ __align__(16) ushort_t As[128 * 32];
    __shared__ __align__(16) ushort_t Bs[128 * 32];
    const ushort_t* A = P + (size_t)b * 2048 * 2048 + (size_t)bm * 128 * 2048;
    const ushort_t* Bm = Vt + (size_t)b * 1024 * 2048 + (size_t)bn * 128 * 2048;
    const int lane = tid & 63, wid = tid >> 6;
    const int wr = wid >> 1, wc = wid & 1;
    f32x4 acc[4][4] = {};
    const int kEnd = (bm + 1) * 128;
    for (int k0 = 0; k0 < kEnd; k0 += 32) {
        stage_tile(A, 2048, k0, As, tid);
        stage_tile(Bm, 2048, k0, Bs, tid);
        __syncthreads();
        const int koff = (lane >> 4) * 8;
        bf16x8 a[4], bb[4];
#pragma unroll
        for (int m = 0; m < 4; ++m)
            a[m] = *(const bf16x8*)&As[(wr * 64 + m * 16 + (lane & 15)) * 32 + koff];
#pragma unroll
        for (int n = 0; n < 4; ++n)
            bb[n] = *(const bf16x8*)&Bs[(wc * 64 + n * 16 + (lane & 15)) * 32 + koff];
#pragma unroll
        for (int m = 0; m < 4; ++m)
#pragma unroll
            for (int n = 0; n < 4; ++n)
                acc[m][n] = __builtin_amdgcn_mfma_f32_16x16x32_bf16(a[m], bb[n], acc[m][n], 0, 0, 0);
        __syncthreads();
    }
    float* Ob = O + (size_t)b * 2048 * 1024 + (size_t)bm * 128 * 1024 + bn * 128;
#pragma unroll
    for (int m = 0; m < 4; ++m)
#pragma unroll
        for (int n = 0; n < 4; ++n)
#pragma unroll
            for (int j = 0; j < 4; ++j) {
                int row = wr * 64 + m * 16 + (lane >> 4) * 4 + j;
                int col = wc * 64 + n * 16 + (lane & 15);
                Ob[(size_t)row * 1024 + col] = acc[m][n][j];
            }
}

// ---------------------------------------------------------------------------
// Workspace (bf16 elems), 48M total (1M = 1024*1024):
//   P    @ 0     (16M)  -- written by scores (after Bmat consumed)
//     WqT  @ 0   (1M), WkT @ 1M (1M), Bmat @ 2M (2M: Mt rows 0-1023,
//     Wv-bf16 rows 1024-2047)  -- all dead before scores writes P
//   Xb   @ 16M  (8M)  -- alive through scores (B operand of T1@X^T)
//   T1   @ 24M  (8M)
//   V    @ 32M  (8M)
//   Vt   @ 40M  (8M)
// ---------------------------------------------------------------------------
extern "C" void kernel_launch(void* const* d_in, const int* in_sizes, int n_in,
                              void* d_out, int out_size, void* d_ws, size_t ws_size,
                              hipStream_t stream) {
    const float* x  = (const float*)d_in[0];
    const float* Wq = (const float*)d_in[1];
    const float* Wk = (const float*)d_in[2];
    const float* Wv = (const float*)d_in[3];
    float* out = (float*)d_out;
    ushort_t* ws = (ushort_t*)d_ws;
    const size_t M1 = (size_t)1024 * 1024;
    ushort_t* P    = ws;
    ushort_t* WqT  = ws;
    ushort_t* WkT  = ws + M1;
    ushort_t* Bmat = ws + 2 * M1;
    ushort_t* Xb   = ws + 16 * M1;
    ushort_t* T1   = ws + 24 * M1;
    ushort_t* V    = ws + 32 * M1;
    ushort_t* Vt   = ws + 40 * M1;

    conv_x<<<dim3(4096 + 512), 256, 0, stream>>>(x, Wv, Xb, Bmat + M1);
    convT_w<<<dim3(16, 16, 2), 256, 0, stream>>>(Wq, Wk, WqT, WkT);
    mt_gemm<<<dim3(8, 8), 256, 0, stream>>>(WkT, WqT, Bmat);
    t1v_gemm256<<<dim3(8, 32), 1024, 0, stream>>>(Xb, Bmat, T1, V);
    scores_gemm256<<<dim3(8, 8, 4), 1024, 0, stream>>>(T1, Xb, P, V, Vt);
    softmax_rows<<<dim3(2048, 4), 256, 0, stream>>>(P);
    pv_gemm<<<dim3(8, 16, 4), 256, 0, stream>>>(P, Vt, out);
}

// Round 8
// 162.843 us; speedup vs baseline: 1.5987x; 1.0894x over previous
//
#include <hip/hip_runtime.h>
#include <hip/hip_bf16.h>

typedef unsigned int uint32;
typedef unsigned short ushort_t;

typedef __bf16 bf16x8 __attribute__((ext_vector_type(8)));
typedef float f32x4 __attribute__((ext_vector_type(4)));

__device__ __forceinline__ ushort_t f2bf(float f) {
    uint32 u = __float_as_uint(f);
    u += 0x7fffu + ((u >> 16) & 1u);
    return (ushort_t)(u >> 16);
}
__device__ __forceinline__ float bf2f(ushort_t h) {
    return __uint_as_float(((uint32)h) << 16);
}

union U16 { int4 v; ushort_t u[8]; };

// async global->LDS, 16B per lane (dest = wave-uniform base + lane*16)
__device__ __forceinline__ void gll16(const ushort_t* g, ushort_t* l) {
    __builtin_amdgcn_global_load_lds(
        (const __attribute__((address_space(1))) unsigned int*)g,
        (__attribute__((address_space(3))) unsigned int*)l, 16, 0, 0);
}

#define SBAR() __builtin_amdgcn_s_barrier()
#define VM0()  asm volatile("s_waitcnt vmcnt(0)" ::: "memory")
#define VM1()  asm volatile("s_waitcnt vmcnt(1)" ::: "memory")
#define VM2()  asm volatile("s_waitcnt vmcnt(2)" ::: "memory")

// swizzled LDS fragment offset (BK=32): row r, k-offset kk in {0,8,16,24}
__device__ __forceinline__ int frag3(int r, int kk) {
    return r * 32 + ((((kk >> 3) ^ ((r >> 1) & 3))) << 3);
}

// ===========================================================================
// 256x256 GEMM, BK=32, 1024 threads = 16 waves (4M x 4N), wave tile 64x64.
// 3-buffer LDS ring (96KB), one barrier per K-tile, counted vmcnt.
// Measured (R6): Tblock ~= 32.5us @ NT=32, bank conflicts 0.
// ===========================================================================
template<int NT>
__device__ __forceinline__ void gemm256_bk32(
    const ushort_t* __restrict__ A, int lda,
    const ushort_t* __restrict__ B, int ldb,
    ushort_t* lds, f32x4 acc[4][4])
{
    const int tid = threadIdx.x;
    const int lane = tid & 63, wid = tid >> 6;
    const int wm = wid >> 2, wn = wid & 3;
    const int l15 = lane & 15, kk = (lane >> 4) * 8;
    const int srow = tid >> 2;
    const int sc4 = (tid & 3) ^ ((tid >> 3) & 3);   // inverse swizzle on src

    #define STAGE3(G, ldg, X, op)                                            \
        gll16(&(G)[(size_t)srow * (ldg) + (X) * 32 + sc4 * 8],               \
              &lds[(((X) % 3) * 2 + (op)) * 8192 + tid * 8])

    STAGE3(A, lda, 0, 0);
    STAGE3(B, ldb, 0, 1);
    if (NT > 1) { STAGE3(B, ldb, 1, 1); VM1(); } else { VM0(); }
    SBAR();

    for (int t = 0; t < NT; ++t) {
        const ushort_t* Ab = lds + (t % 3) * 16384;
        const ushort_t* Bb = Ab + 8192;
        if (t + 1 < NT) STAGE3(A, lda, t + 1, 0);
        if (t + 2 < NT) STAGE3(B, ldb, t + 2, 1);
        bf16x8 af[4], bfr[4];
#pragma unroll
        for (int m = 0; m < 4; ++m)
            af[m] = *(const bf16x8*)&Ab[frag3(wm * 64 + m * 16 + l15, kk)];
#pragma unroll
        for (int n = 0; n < 4; ++n)
            bfr[n] = *(const bf16x8*)&Bb[frag3(wn * 64 + n * 16 + l15, kk)];
#pragma unroll
        for (int m = 0; m < 4; ++m)
#pragma unroll
            for (int n = 0; n < 4; ++n)
                acc[m][n] = __builtin_amdgcn_mfma_f32_16x16x32_bf16(
                    af[m], bfr[n], acc[m][n], 0, 0, 0);
        if (t + 1 < NT) {
            if (t + 2 < NT) VM1(); else VM0();
            SBAR();
        }
    }
    #undef STAGE3
}

// ===========================================================================
// 128x128 GEMM, BK=32, 256 threads = 4 waves (2x2), wave tile 64x64.
// Same swizzled 3-ring/counted-vmcnt structure; 48KB LDS -> 3 blocks/CU
// (12 waves/CU: blocks cover each other's barriers). Runtime NT.
// vmcnt: 2 loads per stage-op => boundary waits vmcnt(2) (B(t+2) in flight).
// ===========================================================================
__device__ __forceinline__ void gemm128_bk32(
    const ushort_t* __restrict__ A, int lda,
    const ushort_t* __restrict__ B, int ldb,
    ushort_t* lds, int NT, f32x4 acc[4][4])
{
    const int tid = threadIdx.x;
    const int lane = tid & 63, wid = tid >> 6;
    const int wm = wid >> 1, wn = wid & 1;
    const int l15 = lane & 15, kk = (lane >> 4) * 8;

    #define STG128(G, ldg, X, op) do {                                       \
        _Pragma("unroll")                                                    \
        for (int i = 0; i < 2; ++i) {                                        \
            int c = i * 256 + tid;          /* 0..511, 16B chunks */         \
            int row = c >> 2;                                                \
            int slot = (c & 3) ^ ((row >> 1) & 3);                           \
            gll16(&(G)[(size_t)row * (ldg) + (X) * 32 + slot * 8],           \
                  &lds[(((X) % 3) * 2 + (op)) * 4096 + c * 8]);              \
        } } while (0)

    STG128(A, lda, 0, 0);
    STG128(B, ldb, 0, 1);
    if (NT > 1) { STG128(B, ldb, 1, 1); VM2(); } else { VM0(); }
    SBAR();

    for (int t = 0; t < NT; ++t) {
        const ushort_t* Ab = lds + (t % 3) * 8192;
        const ushort_t* Bb = Ab + 4096;
        if (t + 1 < NT) STG128(A, lda, t + 1, 0);
        if (t + 2 < NT) STG128(B, ldb, t + 2, 1);
        bf16x8 af[4], bfr[4];
#pragma unroll
        for (int m = 0; m < 4; ++m)
            af[m] = *(const bf16x8*)&Ab[frag3(wm * 64 + m * 16 + l15, kk)];
#pragma unroll
        for (int n = 0; n < 4; ++n)
            bfr[n] = *(const bf16x8*)&Bb[frag3(wn * 64 + n * 16 + l15, kk)];
#pragma unroll
        for (int m = 0; m < 4; ++m)
#pragma unroll
            for (int n = 0; n < 4; ++n)
                acc[m][n] = __builtin_amdgcn_mfma_f32_16x16x32_bf16(
                    af[m], bfr[n], acc[m][n], 0, 0, 0);
        if (t + 1 < NT) {
            if (t + 2 < NT) VM2(); else VM0();
            SBAR();
        }
    }
    #undef STG128
}

// ---------------------------------------------------------------------------
// Kernel 0: fp32 -> bf16: X (gb<4096) and Wv -> Bmat rows 1024..2047.
// ---------------------------------------------------------------------------
__global__ __launch_bounds__(256) void conv_x(
    const float* __restrict__ X, const float* __restrict__ Wv,
    ushort_t* __restrict__ Xb, ushort_t* __restrict__ BmatV)
{
    int gb = blockIdx.x;
    const float* src;
    ushort_t* dst;
    if (gb < 4096) {
        size_t base = ((size_t)gb * 256 + threadIdx.x) * 8;
        src = X + base; dst = Xb + base;
    } else {
        size_t base = ((size_t)(gb - 4096) * 256 + threadIdx.x) * 8;
        src = Wv + base; dst = BmatV + base;
    }
    float4 f0 = *(const float4*)src;
    float4 f1 = *(const float4*)(src + 4);
    U16 o;
    o.u[0] = f2bf(f0.x); o.u[1] = f2bf(f0.y); o.u[2] = f2bf(f0.z); o.u[3] = f2bf(f0.w);
    o.u[4] = f2bf(f1.x); o.u[5] = f2bf(f1.y); o.u[6] = f2bf(f1.z); o.u[7] = f2bf(f1.w);
    *(int4*)dst = o.v;
}

// ---------------------------------------------------------------------------
// Kernel 0b: transpose+convert Wq,Wk: dstT[d][o] = src[o][d], fp32 -> bf16.
// grid (16,16,2), 64x64 tiles.
// ---------------------------------------------------------------------------
__global__ __launch_bounds__(256) void convT_w(
    const float* __restrict__ Wq, const float* __restrict__ Wk,
    ushort_t* __restrict__ WqT, ushort_t* __restrict__ WkT)
{
    __shared__ ushort_t ts[64][72];
    const float* W = blockIdx.z ? Wk : Wq;
    ushort_t* Dt = blockIdx.z ? WkT : WqT;
    const int o0 = blockIdx.x * 64, d0 = blockIdx.y * 64;
    const int tid = threadIdx.x;
    const int row = tid >> 2, q = tid & 3;
#pragma unroll
    for (int c4 = 0; c4 < 4; ++c4) {
        float4 f = *(const float4*)&W[(size_t)(o0 + row) * 1024 + d0 + q * 16 + c4 * 4];
        ts[row][q * 16 + c4 * 4 + 0] = f2bf(f.x);
        ts[row][q * 16 + c4 * 4 + 1] = f2bf(f.y);
        ts[row][q * 16 + c4 * 4 + 2] = f2bf(f.z);
        ts[row][q * 16 + c4 * 4 + 3] = f2bf(f.w);
    }
    __syncthreads();
#pragma unroll
    for (int i = 0; i < 2; ++i) {
        int c = tid + 256 * i;
        int drow = c >> 3, ocol8 = c & 7;
        U16 vv;
#pragma unroll
        for (int j = 0; j < 8; ++j) vv.u[j] = ts[ocol8 * 8 + j][drow];
        *(int4*)&Dt[(size_t)(d0 + drow) * 1024 + o0 + ocol8 * 8] = vv.v;
    }
}

// ---------------------------------------------------------------------------
// Kernel 0c: Mt GEMM: Bmat[a][d] = sum_o WkT[a][o]*WqT[d][o]. grid (8,8).
// (swizzled 128^2 structure, NT=32)
// ---------------------------------------------------------------------------
__global__ __launch_bounds__(256) void mt_gemm(
    const ushort_t* __restrict__ WkT, const ushort_t* __restrict__ WqT,
    ushort_t* __restrict__ Bmat)
{
    __shared__ __align__(16) ushort_t lds[24576];  // 48 KB
    const int bm = blockIdx.y, bn = blockIdx.x;
    const int tid = threadIdx.x;
    f32x4 acc[4][4] = {};
    gemm128_bk32(WkT + (size_t)bm * 128 * 1024, 1024,
                 WqT + (size_t)bn * 128 * 1024, 1024, lds, 32, acc);
    ushort_t* Dst = Bmat + (size_t)bm * 128 * 1024 + bn * 128;
    const int lane = tid & 63, wid = tid >> 6;
    const int wr = wid >> 1, wc = wid & 1;
#pragma unroll
    for (int m = 0; m < 4; ++m)
#pragma unroll
        for (int n = 0; n < 4; ++n)
#pragma unroll
            for (int j = 0; j < 4; ++j) {
                int row = wr * 64 + m * 16 + (lane >> 4) * 4 + j;
                int col = wc * 64 + n * 16 + (lane & 15);
                Dst[(size_t)row * 1024 + col] = f2bf(acc[m][n][j]);
            }
}

// ---------------------------------------------------------------------------
// Kernel 1: T1|V projection: [8192][1024] @ Bmat[2048][1024]^T.
// grid (8,32) = 256 blocks = exactly 1 occupancy round. 1024 thr.
// ---------------------------------------------------------------------------
__global__ __launch_bounds__(1024) void t1v_gemm256(
    const ushort_t* __restrict__ Xb, const ushort_t* __restrict__ Bmat,
    ushort_t* __restrict__ T1, ushort_t* __restrict__ V)
{
    __shared__ __align__(16) ushort_t lds[49152];  // 96 KB
    const int bm = blockIdx.y, bn = blockIdx.x;
    f32x4 acc[4][4] = {};
    gemm256_bk32<32>(Xb + (size_t)bm * 256 * 1024, 1024,
                     Bmat + (size_t)bn * 256 * 1024, 1024, lds, acc);
    ushort_t* Dst = ((bn < 4) ? T1 : V)
                  + (size_t)bm * 256 * 1024 + (bn & 3) * 256;
    const int tid = threadIdx.x, lane = tid & 63, wid = tid >> 6;
    const int wm = wid >> 2, wn = wid & 3;
#pragma unroll
    for (int m = 0; m < 4; ++m)
#pragma unroll
        for (int n = 0; n < 4; ++n)
#pragma unroll
            for (int j = 0; j < 4; ++j) {
                int row = wm * 64 + m * 16 + (lane >> 4) * 4 + j;
                int col = wn * 64 + n * 16 + (lane & 15);
                Dst[(size_t)row * 1024 + col] = f2bf(acc[m][n][j]);
            }
}

// ---------------------------------------------------------------------------
// Kernel 2: scores = (T1 @ X^T)/32, 256^2 BK=32 16-wave, causal block-skip;
// masked blocks (bn > bm) do the V-transpose instead. grid (8,8,4), 1024 thr.
// ---------------------------------------------------------------------------
__global__ __launch_bounds__(1024) void scores_gemm256(
    const ushort_t* __restrict__ T1, const ushort_t* __restrict__ Xb,
    ushort_t* __restrict__ P,
    const ushort_t* __restrict__ V, ushort_t* __restrict__ Vt)
{
    __shared__ __align__(16) ushort_t lds[49152];
    const int b = blockIdx.z, bm = blockIdx.y, bn = blockIdx.x;
    const int tid = threadIdx.x;
    if (bn > bm) {
        // ---- V-transpose duty: 512 64x64 tiles/batch over 28 masked blocks
        ushort_t (*ts)[72] = (ushort_t(*)[72])lds;
        const ushort_t* Vb = V + (size_t)b * 2048 * 1024;
        ushort_t* Vtb = Vt + (size_t)b * 1024 * 2048;
        const int rank = bn * (bn - 1) / 2 + bm;   // [0,28)
        for (int t = rank; t < 512; t += 28) {
            int k0 = (t >> 4) * 64, d0 = (t & 15) * 64;
            __syncthreads();
            if (tid < 512) {
                int row = tid >> 3, col8 = tid & 7;
                U16 vv;
                vv.v = *(const int4*)&Vb[(size_t)(k0 + row) * 1024 + d0 + col8 * 8];
#pragma unroll
                for (int j = 0; j < 8; ++j) ts[row][col8 * 8 + j] = vv.u[j];
            }
            __syncthreads();
            if (tid < 512) {
                int drow = tid >> 3, kcol8 = tid & 7;
                U16 vv;
#pragma unroll
                for (int j = 0; j < 8; ++j) vv.u[j] = ts[kcol8 * 8 + j][drow];
                *(int4*)&Vtb[(size_t)(d0 + drow) * 2048 + k0 + kcol8 * 8] = vv.v;
            }
        }
        return;
    }
    f32x4 acc[4][4] = {};
    gemm256_bk32<32>(T1 + (size_t)b * 2048 * 1024 + (size_t)bm * 256 * 1024, 1024,
                     Xb + (size_t)b * 2048 * 1024 + (size_t)bn * 256 * 1024, 1024,
                     lds, acc);
    ushort_t* Pb = P + (size_t)b * 2048 * 2048 + (size_t)bm * 256 * 2048 + bn * 256;
    const int lane = tid & 63, wid = tid >> 6;
    const int wm = wid >> 2, wn = wid & 3;
#pragma unroll
    for (int m = 0; m < 4; ++m)
#pragma unroll
        for (int n = 0; n < 4; ++n)
#pragma unroll
            for (int j = 0; j < 4; ++j) {
                int row = wm * 64 + m * 16 + (lane >> 4) * 4 + j;
                int col = wn * 64 + n * 16 + (lane & 15);
                Pb[(size_t)row * 2048 + col] = f2bf(acc[m][n][j] * 0.03125f);
            }
}

// ---------------------------------------------------------------------------
// Kernel 3: row softmax in place on P (bf16), causal by index.
// Only touches k < kmax = ((q>>7)+1)*128 — pv never reads beyond.
// ---------------------------------------------------------------------------
__global__ __launch_bounds__(256) void softmax_rows(ushort_t* __restrict__ P)
{
    const int q = blockIdx.x, b = blockIdx.y;
    ushort_t* row = P + ((size_t)b * 2048 + q) * 2048;
    const int tid = threadIdx.x;
    const int kmax = ((q >> 7) + 1) * 128;
    const bool active = tid * 8 < kmax;
    float v[8];
    float m = -3.0e38f;
    if (active) {
        U16 in;
        in.v = *(const int4*)&row[tid * 8];
#pragma unroll
        for (int j = 0; j < 8; ++j) {
            int k = tid * 8 + j;
            float s = bf2f(in.u[j]);
            v[j] = (k <= q) ? s : -3.0e38f;
            m = fmaxf(m, v[j]);
        }
    } else {
#pragma unroll
        for (int j = 0; j < 8; ++j) v[j] = -3.0e38f;
    }
#pragma unroll
    for (int off = 32; off >= 1; off >>= 1) m = fmaxf(m, __shfl_xor(m, off));
    __shared__ float red[4];
    if ((tid & 63) == 0) red[tid >> 6] = m;
    __syncthreads();
    m = fmaxf(fmaxf(red[0], red[1]), fmaxf(red[2], red[3]));
    float e[8], s = 0.f;
#pragma unroll
    for (int j = 0; j < 8; ++j) {
        e[j] = (v[j] > -1.0e38f) ? __expf(v[j] - m) : 0.f;
        s += e[j];
    }
#pragma unroll
    for (int off = 32; off >= 1; off >>= 1) s += __shfl_xor(s, off);
    __syncthreads();
    if ((tid & 63) == 0) red[tid >> 6] = s;
    __syncthreads();
    s = red[0] + red[1] + red[2] + red[3];
    float inv = 1.f / s;
    if (active) {
        U16 outv;
#pragma unroll
        for (int j = 0; j < 8; ++j) outv.u[j] = f2bf(e[j] * inv);
        *(int4*)&row[tid * 8] = outv.v;
    }
}

// ---------------------------------------------------------------------------
// Kernel 5: O = P @ V via Vt, swizzled 3-ring 128^2, K capped at diagonal.
// grid (8, 16, 4); 512 blocks, 3 blocks/CU -> all resident. Balanced pairing:
// bm = y<8 ? 15-2y : 2y-16 (each CU's two blocks sum to ~17*128 K-units).
// ---------------------------------------------------------------------------
__global__ __launch_bounds__(256) void pv_gemm(
    const ushort_t* __restrict__ P, const ushort_t* __restrict__ Vt,
    float* __restrict__ O)
{
    __shared__ __align__(16) ushort_t lds[24576];  // 48 KB
    const int b = blockIdx.z;
    const int y = blockIdx.y;
    const int bm = (y < 8) ? (15 - 2 * y) : (2 * y - 16);
    const int bn = blockIdx.x;
    const int tid = threadIdx.x;
    const ushort_t* A = P + (size_t)b * 2048 * 2048 + (size_t)bm * 128 * 2048;
    const ushort_t* Bm = Vt + (size_t)b * 1024 * 2048 + (size_t)bn * 128 * 2048;
    f32x4 acc[4][4] = {};
    const int NT = (bm + 1) * 4;   // K = (bm+1)*128, BK=32
    gemm128_bk32(A, 2048, Bm, 2048, lds, NT, acc);
    float* Ob = O + (size_t)b * 2048 * 1024 + (size_t)bm * 128 * 1024 + bn * 128;
    const int lane = tid & 63, wid = tid >> 6;
    const int wr = wid >> 1, wc = wid & 1;
#pragma unroll
    for (int m = 0; m < 4; ++m)
#pragma unroll
        for (int n = 0; n < 4; ++n)
#pragma unroll
            for (int j = 0; j < 4; ++j) {
                int row = wr * 64 + m * 16 + (lane >> 4) * 4 + j;
                int col = wc * 64 + n * 16 + (lane & 15);
                Ob[(size_t)row * 1024 + col] = acc[m][n][j];
            }
}

// ---------------------------------------------------------------------------
// Workspace (bf16 elems), 48M total (1M = 1024*1024):
//   P    @ 0     (16M)  -- written by scores (after Bmat consumed)
//     WqT @ 0 (1M), WkT @ 1M (1M), Bmat @ 2M (2M: Mt rows 0-1023,
//     Wv-bf16 rows 1024-2047)  -- dead before scores writes P
//   Xb   @ 16M  (8M)  -- alive through scores
//   T1   @ 24M  (8M)
//   V    @ 32M  (8M)
//   Vt   @ 40M  (8M)
// ---------------------------------------------------------------------------
extern "C" void kernel_launch(void* const* d_in, const int* in_sizes, int n_in,
                              void* d_out, int out_size, void* d_ws, size_t ws_size,
                              hipStream_t stream) {
    const float* x  = (const float*)d_in[0];
    const float* Wq = (const float*)d_in[1];
    const float* Wk = (const float*)d_in[2];
    const float* Wv = (const float*)d_in[3];
    float* out = (float*)d_out;
    ushort_t* ws = (ushort_t*)d_ws;
    const size_t M1 = (size_t)1024 * 1024;
    ushort_t* P    = ws;
    ushort_t* WqT  = ws;
    ushort_t* WkT  = ws + M1;
    ushort_t* Bmat = ws + 2 * M1;
    ushort_t* Xb   = ws + 16 * M1;
    ushort_t* T1   = ws + 24 * M1;
    ushort_t* V    = ws + 32 * M1;
    ushort_t* Vt   = ws + 40 * M1;

    conv_x<<<dim3(4096 + 512), 256, 0, stream>>>(x, Wv, Xb, Bmat + M1);
    convT_w<<<dim3(16, 16, 2), 256, 0, stream>>>(Wq, Wk, WqT, WkT);
    mt_gemm<<<dim3(8, 8), 256, 0, stream>>>(WkT, WqT, Bmat);
    t1v_gemm256<<<dim3(8, 32), 1024, 0, stream>>>(Xb, Bmat, T1, V);
    scores_gemm256<<<dim3(8, 8, 4), 1024, 0, stream>>>(T1, Xb, P, V, Vt);
    softmax_rows<<<dim3(2048, 4), 256, 0, stream>>>(P);
    pv_gemm<<<dim3(8, 16, 4), 256, 0, stream>>>(P, Vt, out);
}

// Round 9
// 148.343 us; speedup vs baseline: 1.7549x; 1.0977x over previous
//
#include <hip/hip_runtime.h>
#include <hip/hip_bf16.h>

typedef unsigned int uint32;
typedef unsigned short ushort_t;

typedef __bf16 bf16x8 __attribute__((ext_vector_type(8)));
typedef float f32x4 __attribute__((ext_vector_type(4)));

__device__ __forceinline__ ushort_t f2bf(float f) {
    uint32 u = __float_as_uint(f);
    u += 0x7fffu + ((u >> 16) & 1u);
    return (ushort_t)(u >> 16);
}
__device__ __forceinline__ float bf2f(ushort_t h) {
    return __uint_as_float(((uint32)h) << 16);
}

union U16 { int4 v; ushort_t u[8]; };

// async global->LDS, 16B per lane (dest = wave-uniform base + lane*16)
__device__ __forceinline__ void gll16(const ushort_t* g, ushort_t* l) {
    __builtin_amdgcn_global_load_lds(
        (const __attribute__((address_space(1))) unsigned int*)g,
        (__attribute__((address_space(3))) unsigned int*)l, 16, 0, 0);
}

#define SBAR() __builtin_amdgcn_s_barrier()
#define VM0()  asm volatile("s_waitcnt vmcnt(0)" ::: "memory")
#define VM1()  asm volatile("s_waitcnt vmcnt(1)" ::: "memory")
#define VM2()  asm volatile("s_waitcnt vmcnt(2)" ::: "memory")

// swizzled LDS fragment offset (BK=32): row r, k-offset kk in {0,8,16,24}
__device__ __forceinline__ int frag3(int r, int kk) {
    return r * 32 + ((((kk >> 3) ^ ((r >> 1) & 3))) << 3);
}

// ===========================================================================
// 256x256 GEMM, BK=32, 1024 threads = 16 waves (4M x 4N), wave tile 64x64.
// 3-buffer LDS ring (96KB), one barrier per K-tile, counted vmcnt.
// Measured (R6): Tblock ~= 32.5us @ NT=32, bank conflicts 0.
// Per-block limiter is operand FETCH (32KB/K-tile): XCD swizzle at call site.
// ===========================================================================
template<int NT>
__device__ __forceinline__ void gemm256_bk32(
    const ushort_t* __restrict__ A, int lda,
    const ushort_t* __restrict__ B, int ldb,
    ushort_t* lds, f32x4 acc[4][4])
{
    const int tid = threadIdx.x;
    const int lane = tid & 63, wid = tid >> 6;
    const int wm = wid >> 2, wn = wid & 3;
    const int l15 = lane & 15, kk = (lane >> 4) * 8;
    const int srow = tid >> 2;
    const int sc4 = (tid & 3) ^ ((tid >> 3) & 3);   // inverse swizzle on src

    #define STAGE3(G, ldg, X, op)                                            \
        gll16(&(G)[(size_t)srow * (ldg) + (X) * 32 + sc4 * 8],               \
              &lds[(((X) % 3) * 2 + (op)) * 8192 + tid * 8])

    STAGE3(A, lda, 0, 0);
    STAGE3(B, ldb, 0, 1);
    if (NT > 1) { STAGE3(B, ldb, 1, 1); VM1(); } else { VM0(); }
    SBAR();

    for (int t = 0; t < NT; ++t) {
        const ushort_t* Ab = lds + (t % 3) * 16384;
        const ushort_t* Bb = Ab + 8192;
        if (t + 1 < NT) STAGE3(A, lda, t + 1, 0);
        if (t + 2 < NT) STAGE3(B, ldb, t + 2, 1);
        bf16x8 af[4], bfr[4];
#pragma unroll
        for (int m = 0; m < 4; ++m)
            af[m] = *(const bf16x8*)&Ab[frag3(wm * 64 + m * 16 + l15, kk)];
#pragma unroll
        for (int n = 0; n < 4; ++n)
            bfr[n] = *(const bf16x8*)&Bb[frag3(wn * 64 + n * 16 + l15, kk)];
#pragma unroll
        for (int m = 0; m < 4; ++m)
#pragma unroll
            for (int n = 0; n < 4; ++n)
                acc[m][n] = __builtin_amdgcn_mfma_f32_16x16x32_bf16(
                    af[m], bfr[n], acc[m][n], 0, 0, 0);
        if (t + 1 < NT) {
            if (t + 2 < NT) VM1(); else VM0();
            SBAR();
        }
    }
    #undef STAGE3
}

// ===========================================================================
// 128x128 GEMM, BK=32, 256 threads = 4 waves (2x2), wave tile 64x64.
// Same swizzled 3-ring/counted-vmcnt structure; 48KB LDS -> 3 blocks/CU.
// ===========================================================================
__device__ __forceinline__ void gemm128_bk32(
    const ushort_t* __restrict__ A, int lda,
    const ushort_t* __restrict__ B, int ldb,
    ushort_t* lds, int NT, f32x4 acc[4][4])
{
    const int tid = threadIdx.x;
    const int lane = tid & 63, wid = tid >> 6;
    const int wm = wid >> 1, wn = wid & 1;
    const int l15 = lane & 15, kk = (lane >> 4) * 8;

    #define STG128(G, ldg, X, op) do {                                       \
        _Pragma("unroll")                                                    \
        for (int i = 0; i < 2; ++i) {                                        \
            int c = i * 256 + tid;          /* 0..511, 16B chunks */         \
            int row = c >> 2;                                                \
            int slot = (c & 3) ^ ((row >> 1) & 3);                           \
            gll16(&(G)[(size_t)row * (ldg) + (X) * 32 + slot * 8],           \
                  &lds[(((X) % 3) * 2 + (op)) * 4096 + c * 8]);              \
        } } while (0)

    STG128(A, lda, 0, 0);
    STG128(B, ldb, 0, 1);
    if (NT > 1) { STG128(B, ldb, 1, 1); VM2(); } else { VM0(); }
    SBAR();

    for (int t = 0; t < NT; ++t) {
        const ushort_t* Ab = lds + (t % 3) * 8192;
        const ushort_t* Bb = Ab + 4096;
        if (t + 1 < NT) STG128(A, lda, t + 1, 0);
        if (t + 2 < NT) STG128(B, ldb, t + 2, 1);
        bf16x8 af[4], bfr[4];
#pragma unroll
        for (int m = 0; m < 4; ++m)
            af[m] = *(const bf16x8*)&Ab[frag3(wm * 64 + m * 16 + l15, kk)];
#pragma unroll
        for (int n = 0; n < 4; ++n)
            bfr[n] = *(const bf16x8*)&Bb[frag3(wn * 64 + n * 16 + l15, kk)];
#pragma unroll
        for (int m = 0; m < 4; ++m)
#pragma unroll
            for (int n = 0; n < 4; ++n)
                acc[m][n] = __builtin_amdgcn_mfma_f32_16x16x32_bf16(
                    af[m], bfr[n], acc[m][n], 0, 0, 0);
        if (t + 1 < NT) {
            if (t + 2 < NT) VM2(); else VM0();
            SBAR();
        }
    }
    #undef STG128
}

// ---------------------------------------------------------------------------
// Kernel 0: fp32 -> bf16: X (gb<4096) and Wv -> Bmat rows 1024..2047.
// ---------------------------------------------------------------------------
__global__ __launch_bounds__(256) void conv_x(
    const float* __restrict__ X, const float* __restrict__ Wv,
    ushort_t* __restrict__ Xb, ushort_t* __restrict__ BmatV)
{
    int gb = blockIdx.x;
    const float* src;
    ushort_t* dst;
    if (gb < 4096) {
        size_t base = ((size_t)gb * 256 + threadIdx.x) * 8;
        src = X + base; dst = Xb + base;
    } else {
        size_t base = ((size_t)(gb - 4096) * 256 + threadIdx.x) * 8;
        src = Wv + base; dst = BmatV + base;
    }
    float4 f0 = *(const float4*)src;
    float4 f1 = *(const float4*)(src + 4);
    U16 o;
    o.u[0] = f2bf(f0.x); o.u[1] = f2bf(f0.y); o.u[2] = f2bf(f0.z); o.u[3] = f2bf(f0.w);
    o.u[4] = f2bf(f1.x); o.u[5] = f2bf(f1.y); o.u[6] = f2bf(f1.z); o.u[7] = f2bf(f1.w);
    *(int4*)dst = o.v;
}

// ---------------------------------------------------------------------------
// Kernel 0b: transpose+convert Wq,Wk: dstT[d][o] = src[o][d], fp32 -> bf16.
// grid (16,16,2), 64x64 tiles.
// ---------------------------------------------------------------------------
__global__ __launch_bounds__(256) void convT_w(
    const float* __restrict__ Wq, const float* __restrict__ Wk,
    ushort_t* __restrict__ WqT, ushort_t* __restrict__ WkT)
{
    __shared__ ushort_t ts[64][72];
    const float* W = blockIdx.z ? Wk : Wq;
    ushort_t* Dt = blockIdx.z ? WkT : WqT;
    const int o0 = blockIdx.x * 64, d0 = blockIdx.y * 64;
    const int tid = threadIdx.x;
    const int row = tid >> 2, q = tid & 3;
#pragma unroll
    for (int c4 = 0; c4 < 4; ++c4) {
        float4 f = *(const float4*)&W[(size_t)(o0 + row) * 1024 + d0 + q * 16 + c4 * 4];
        ts[row][q * 16 + c4 * 4 + 0] = f2bf(f.x);
        ts[row][q * 16 + c4 * 4 + 1] = f2bf(f.y);
        ts[row][q * 16 + c4 * 4 + 2] = f2bf(f.z);
        ts[row][q * 16 + c4 * 4 + 3] = f2bf(f.w);
    }
    __syncthreads();
#pragma unroll
    for (int i = 0; i < 2; ++i) {
        int c = tid + 256 * i;
        int drow = c >> 3, ocol8 = c & 7;
        U16 vv;
#pragma unroll
        for (int j = 0; j < 8; ++j) vv.u[j] = ts[ocol8 * 8 + j][drow];
        *(int4*)&Dt[(size_t)(d0 + drow) * 1024 + o0 + ocol8 * 8] = vv.v;
    }
}

// ---------------------------------------------------------------------------
// Kernel 0c: Mt GEMM: Bmat[a][d] = sum_o WkT[a][o]*WqT[d][o]. grid (8,8).
// ---------------------------------------------------------------------------
__global__ __launch_bounds__(256) void mt_gemm(
    const ushort_t* __restrict__ WkT, const ushort_t* __restrict__ WqT,
    ushort_t* __restrict__ Bmat)
{
    __shared__ __align__(16) ushort_t lds[24576];  // 48 KB
    const int bm = blockIdx.y, bn = blockIdx.x;
    const int tid = threadIdx.x;
    f32x4 acc[4][4] = {};
    gemm128_bk32(WkT + (size_t)bm * 128 * 1024, 1024,
                 WqT + (size_t)bn * 128 * 1024, 1024, lds, 32, acc);
    ushort_t* Dst = Bmat + (size_t)bm * 128 * 1024 + bn * 128;
    const int lane = tid & 63, wid = tid >> 6;
    const int wr = wid >> 1, wc = wid & 1;
#pragma unroll
    for (int m = 0; m < 4; ++m)
#pragma unroll
        for (int n = 0; n < 4; ++n)
#pragma unroll
            for (int j = 0; j < 4; ++j) {
                int row = wr * 64 + m * 16 + (lane >> 4) * 4 + j;
                int col = wc * 64 + n * 16 + (lane & 15);
                Dst[(size_t)row * 1024 + col] = f2bf(acc[m][n][j]);
            }
}

// ---------------------------------------------------------------------------
// Kernel 1: T1|V projection: [8192][1024] @ Bmat[2048][1024]^T.
// 1-D grid 256, XCD-swizzled (T1): xcd = id&7 owns bm in [4*xcd, 4*xcd+4)
// x all bn -> 6MB/XCD working set (L2-resident). 1024 thr.
// ---------------------------------------------------------------------------
__global__ __launch_bounds__(1024) void t1v_gemm256(
    const ushort_t* __restrict__ Xb, const ushort_t* __restrict__ Bmat,
    ushort_t* __restrict__ T1, ushort_t* __restrict__ V)
{
    __shared__ __align__(16) ushort_t lds[49152];  // 96 KB
    const int id = blockIdx.x;            // [0,256)
    const int xcd = id & 7, l = id >> 3;  // l in [0,32)
    const int bm = xcd * 4 + (l >> 3);    // [0,32)
    const int bn = l & 7;                 // [0,8)
    f32x4 acc[4][4] = {};
    gemm256_bk32<32>(Xb + (size_t)bm * 256 * 1024, 1024,
                     Bmat + (size_t)bn * 256 * 1024, 1024, lds, acc);
    ushort_t* Dst = ((bn < 4) ? T1 : V)
                  + (size_t)bm * 256 * 1024 + (bn & 3) * 256;
    const int tid = threadIdx.x, lane = tid & 63, wid = tid >> 6;
    const int wm = wid >> 2, wn = wid & 3;
#pragma unroll
    for (int m = 0; m < 4; ++m)
#pragma unroll
        for (int n = 0; n < 4; ++n)
#pragma unroll
            for (int j = 0; j < 4; ++j) {
                int row = wm * 64 + m * 16 + (lane >> 4) * 4 + j;
                int col = wn * 64 + n * 16 + (lane & 15);
                Dst[(size_t)row * 1024 + col] = f2bf(acc[m][n][j]);
            }
}

// ---------------------------------------------------------------------------
// Kernel 2: scores = (T1 @ X^T)/32, 256^2, causal; masked blocks transpose V.
// 1-D grid 256, XCD-swizzled: xcd = (b<<1)|h owns batch b, bm in [4h,4h+4),
// all bn -> 6MB/XCD (T1 2MB + Xb 4MB, batch-local).
// ---------------------------------------------------------------------------
__global__ __launch_bounds__(1024) void scores_gemm256(
    const ushort_t* __restrict__ T1, const ushort_t* __restrict__ Xb,
    ushort_t* __restrict__ P,
    const ushort_t* __restrict__ V, ushort_t* __restrict__ Vt)
{
    __shared__ __align__(16) ushort_t lds[49152];
    const int id = blockIdx.x;            // [0,256)
    const int xcd = id & 7, l = id >> 3;  // l in [0,32)
    const int b = xcd >> 1, h = xcd & 1;
    const int bm = 4 * h + (l >> 3);      // [0,8)
    const int bn = l & 7;                 // [0,8)
    const int tid = threadIdx.x;
    if (bn > bm) {
        // ---- V-transpose duty: 512 64x64 tiles/batch over 28 masked blocks
        ushort_t (*ts)[72] = (ushort_t(*)[72])lds;
        const ushort_t* Vb = V + (size_t)b * 2048 * 1024;
        ushort_t* Vtb = Vt + (size_t)b * 1024 * 2048;
        const int rank = bn * (bn - 1) / 2 + bm;   // [0,28)
        for (int t = rank; t < 512; t += 28) {
            int k0 = (t >> 4) * 64, d0 = (t & 15) * 64;
            __syncthreads();
            if (tid < 512) {
                int row = tid >> 3, col8 = tid & 7;
                U16 vv;
                vv.v = *(const int4*)&Vb[(size_t)(k0 + row) * 1024 + d0 + col8 * 8];
#pragma unroll
                for (int j = 0; j < 8; ++j) ts[row][col8 * 8 + j] = vv.u[j];
            }
            __syncthreads();
            if (tid < 512) {
                int drow = tid >> 3, kcol8 = tid & 7;
                U16 vv;
#pragma unroll
                for (int j = 0; j < 8; ++j) vv.u[j] = ts[kcol8 * 8 + j][drow];
                *(int4*)&Vtb[(size_t)(d0 + drow) * 2048 + k0 + kcol8 * 8] = vv.v;
            }
        }
        return;
    }
    f32x4 acc[4][4] = {};
    gemm256_bk32<32>(T1 + (size_t)b * 2048 * 1024 + (size_t)bm * 256 * 1024, 1024,
                     Xb + (size_t)b * 2048 * 1024 + (size_t)bn * 256 * 1024, 1024,
                     lds, acc);
    ushort_t* Pb = P + (size_t)b * 2048 * 2048 + (size_t)bm * 256 * 2048 + bn * 256;
    const int lane = tid & 63, wid = tid >> 6;
    const int wm = wid >> 2, wn = wid & 3;
#pragma unroll
    for (int m = 0; m < 4; ++m)
#pragma unroll
        for (int n = 0; n < 4; ++n)
#pragma unroll
            for (int j = 0; j < 4; ++j) {
                int row = wm * 64 + m * 16 + (lane >> 4) * 4 + j;
                int col = wn * 64 + n * 16 + (lane & 15);
                Pb[(size_t)row * 2048 + col] = f2bf(acc[m][n][j] * 0.03125f);
            }
}

// ---------------------------------------------------------------------------
// Kernel 3: row softmax in place on P (bf16), causal by index.
// ---------------------------------------------------------------------------
__global__ __launch_bounds__(256) void softmax_rows(ushort_t* __restrict__ P)
{
    const int q = blockIdx.x, b = blockIdx.y;
    ushort_t* row = P + ((size_t)b * 2048 + q) * 2048;
    const int tid = threadIdx.x;
    const int kmax = ((q >> 7) + 1) * 128;
    const bool active = tid * 8 < kmax;
    float v[8];
    float m = -3.0e38f;
    if (active) {
        U16 in;
        in.v = *(const int4*)&row[tid * 8];
#pragma unroll
        for (int j = 0; j < 8; ++j) {
            int k = tid * 8 + j;
            float s = bf2f(in.u[j]);
            v[j] = (k <= q) ? s : -3.0e38f;
            m = fmaxf(m, v[j]);
        }
    } else {
#pragma unroll
        for (int j = 0; j < 8; ++j) v[j] = -3.0e38f;
    }
#pragma unroll
    for (int off = 32; off >= 1; off >>= 1) m = fmaxf(m, __shfl_xor(m, off));
    __shared__ float red[4];
    if ((tid & 63) == 0) red[tid >> 6] = m;
    __syncthreads();
    m = fmaxf(fmaxf(red[0], red[1]), fmaxf(red[2], red[3]));
    float e[8], s = 0.f;
#pragma unroll
    for (int j = 0; j < 8; ++j) {
        e[j] = (v[j] > -1.0e38f) ? __expf(v[j] - m) : 0.f;
        s += e[j];
    }
#pragma unroll
    for (int off = 32; off >= 1; off >>= 1) s += __shfl_xor(s, off);
    __syncthreads();
    if ((tid & 63) == 0) red[tid >> 6] = s;
    __syncthreads();
    s = red[0] + red[1] + red[2] + red[3];
    float inv = 1.f / s;
    if (active) {
        U16 outv;
#pragma unroll
        for (int j = 0; j < 8; ++j) outv.u[j] = f2bf(e[j] * inv);
        *(int4*)&row[tid * 8] = outv.v;
    }
}

// ---------------------------------------------------------------------------
// Kernel 5: O = P @ V via Vt, swizzled 3-ring 128^2, K capped at diagonal.
// 1-D grid 512. Complementary pairing: L<256 -> b in {0,1}, bm=15-(L&15);
// L>=256 -> b in {2,3}, bm=L&15. Per-XCD work = 544 K-units for every XCD
// under round-robin (verified algebra); CU slot-fill pairs heavy+light (17).
// ---------------------------------------------------------------------------
__global__ __launch_bounds__(256) void pv_gemm(
    const ushort_t* __restrict__ P, const ushort_t* __restrict__ Vt,
    float* __restrict__ O)
{
    __shared__ __align__(16) ushort_t lds[24576];  // 48 KB
    const int L = blockIdx.x;   // [0,512)
    int b, bm, bn;
    if (L < 256) {
        int c = L >> 4;
        b = c >> 3; bn = c & 7; bm = 15 - (L & 15);
    } else {
        int L2 = L - 256;
        int c = L2 >> 4;
        b = 2 + (c >> 3); bn = c & 7; bm = L2 & 15;
    }
    const int tid = threadIdx.x;
    const ushort_t* A = P + (size_t)b * 2048 * 2048 + (size_t)bm * 128 * 2048;
    const ushort_t* Bm = Vt + (size_t)b * 1024 * 2048 + (size_t)bn * 128 * 2048;
    f32x4 acc[4][4] = {};
    const int NT = (bm + 1) * 4;   // K = (bm+1)*128, BK=32
    gemm128_bk32(A, 2048, Bm, 2048, lds, NT, acc);
    float* Ob = O + (size_t)b * 2048 * 1024 + (size_t)bm * 128 * 1024 + bn * 128;
    const int lane = tid & 63, wid = tid >> 6;
    const int wr = wid >> 1, wc = wid & 1;
#pragma unroll
    for (int m = 0; m < 4; ++m)
#pragma unroll
        for (int n = 0; n < 4; ++n)
#pragma unroll
            for (int j = 0; j < 4; ++j) {
                int row = wr * 64 + m * 16 + (lane >> 4) * 4 + j;
                int col = wc * 64 + n * 16 + (lane & 15);
                Ob[(size_t)row * 1024 + col] = acc[m][n][j];
            }
}

// ---------------------------------------------------------------------------
// Workspace (bf16 elems), 48M total (1M = 1024*1024):
//   P    @ 0     (16M)  -- written by scores (after Bmat consumed)
//     WqT @ 0 (1M), WkT @ 1M (1M), Bmat @ 2M (2M) -- dead before P
//   Xb   @ 16M  (8M)  -- alive through scores
//   T1   @ 24M  (8M)
//   V    @ 32M  (8M)
//   Vt   @ 40M  (8M)
// ---------------------------------------------------------------------------
extern "C" void kernel_launch(void* const* d_in, const int* in_sizes, int n_in,
                              void* d_out, int out_size, void* d_ws, size_t ws_size,
                              hipStream_t stream) {
    const float* x  = (const float*)d_in[0];
    const float* Wq = (const float*)d_in[1];
    const float* Wk = (const float*)d_in[2];
    const float* Wv = (const float*)d_in[3];
    float* out = (float*)d_out;
    ushort_t* ws = (ushort_t*)d_ws;
    const size_t M1 = (size_t)1024 * 1024;
    ushort_t* P    = ws;
    ushort_t* WqT  = ws;
    ushort_t* WkT  = ws + M1;
    ushort_t* Bmat = ws + 2 * M1;
    ushort_t* Xb   = ws + 16 * M1;
    ushort_t* T1   = ws + 24 * M1;
    ushort_t* V    = ws + 32 * M1;
    ushort_t* Vt   = ws + 40 * M1;

    conv_x<<<dim3(4096 + 512), 256, 0, stream>>>(x, Wv, Xb, Bmat + M1);
    convT_w<<<dim3(16, 16, 2), 256, 0, stream>>>(Wq, Wk, WqT, WkT);
    mt_gemm<<<dim3(8, 8), 256, 0, stream>>>(WkT, WqT, Bmat);
    t1v_gemm256<<<dim3(256), 1024, 0, stream>>>(Xb, Bmat, T1, V);
    scores_gemm256<<<dim3(256), 1024, 0, stream>>>(T1, Xb, P, V, Vt);
    softmax_rows<<<dim3(2048, 4), 256, 0, stream>>>(P);
    pv_gemm<<<dim3(512), 256, 0, stream>>>(P, Vt, out);
}